// Round 1
// baseline (4597.950 us; speedup 1.0000x reference)
//
#include <hip/hip_runtime.h>
#include <math.h>

// ---------------------------------------------------------------------------
// CapsNet forward, fp32 baseline.
// Pipeline: conv1+relu -> primary conv+bias -> squash -> 3x routing
//           (softmax_c, WC=c*W, s-GEMM, v=f(s), T-GEMM, bp update)
//           -> class softmax/argmax/mask -> 3-layer decoder.
// ---------------------------------------------------------------------------

// ============================ conv1 (1->256, 9x9, s1) ======================
__global__ __launch_bounds__(256) void conv1_kernel(
    const float* __restrict__ data, const float* __restrict__ cw,
    const float* __restrict__ cb, float* __restrict__ x) {
  int ocg = blockIdx.x;   // 0..3, 64 oc each
  int b   = blockIdx.y;   // 0..255
  __shared__ __align__(16) float img[784];       // 28x28
  __shared__ __align__(16) float wsm[64 * 108];  // [oc][kh][12] padded rows
  int t = threadIdx.x;
  for (int i = t; i < 784; i += 256) img[i] = data[b * 784 + i];
  for (int i = t; i < 64 * 81; i += 256) {
    int oc = i / 81, k = i % 81;
    int kh = k / 9, kw = k % 9;
    wsm[oc * 108 + kh * 12 + kw] = cw[(ocg * 64 + oc) * 81 + k];
  }
  __syncthreads();
  // 64 oc * 100 quad-groups (4 consecutive pw per group) = 6400 items
  for (int idx = t; idx < 6400; idx += 256) {
    int oc = idx / 100, q = idx % 100;
    int ph = q / 5, pw0 = (q % 5) * 4;
    float a0 = 0.f, a1 = 0.f, a2 = 0.f, a3 = 0.f;
#pragma unroll
    for (int kh = 0; kh < 9; ++kh) {
      const float4* ir4 = reinterpret_cast<const float4*>(&img[(ph + kh) * 28 + pw0]);
      float4 i0 = ir4[0], i1 = ir4[1], i2 = ir4[2];
      float im[12] = {i0.x, i0.y, i0.z, i0.w, i1.x, i1.y, i1.z, i1.w,
                      i2.x, i2.y, i2.z, i2.w};
      const float4* wr4 = reinterpret_cast<const float4*>(&wsm[oc * 108 + kh * 12]);
      float4 w0 = wr4[0], w1 = wr4[1], w2 = wr4[2];
      float wr[9] = {w0.x, w0.y, w0.z, w0.w, w1.x, w1.y, w1.z, w1.w, w2.x};
#pragma unroll
      for (int kw = 0; kw < 9; ++kw) {
        a0 = fmaf(wr[kw], im[kw + 0], a0);
        a1 = fmaf(wr[kw], im[kw + 1], a1);
        a2 = fmaf(wr[kw], im[kw + 2], a2);
        a3 = fmaf(wr[kw], im[kw + 3], a3);
      }
    }
    float bias = cb[ocg * 64 + oc];
    float* xp = &x[((size_t)b * 256 + ocg * 64 + oc) * 400 + ph * 20 + pw0];
    xp[0] = fmaxf(a0 + bias, 0.f);
    xp[1] = fmaxf(a1 + bias, 0.f);
    xp[2] = fmaxf(a2 + bias, 0.f);
    xp[3] = fmaxf(a3 + bias, 0.f);
  }
}

// =================== primary caps conv (256->256, 9x9, s2) =================
template <int C4, int OFF>
__device__ __forceinline__ void primary_compute(const float* xs, const float* wsm,
                                                int oc, int ph0, float* acc) {
#pragma unroll
  for (int kh = 0; kh < 9; ++kh) {
    const float4* wr4 = reinterpret_cast<const float4*>(&wsm[oc * 108 + kh * 12]);
    float4 w0 = wr4[0], w1 = wr4[1], w2 = wr4[2];
    float wr[9] = {w0.x, w0.y, w0.z, w0.w, w1.x, w1.y, w1.z, w1.w, w2.x};
#pragma unroll
    for (int dp = 0; dp < 3; ++dp) {
      int row = 2 * (ph0 + dp) + kh;
      const float4* x4 = reinterpret_cast<const float4*>(&xs[row * 20 + C4 * 4]);
      float4 xa = x4[0], xb = x4[1], xc = x4[2], xd = x4[3];
      float xr[16] = {xa.x, xa.y, xa.z, xa.w, xb.x, xb.y, xb.z, xb.w,
                      xc.x, xc.y, xc.z, xc.w, xd.x, xd.y, xd.z, xd.w};
#pragma unroll
      for (int dw = 0; dw < 3; ++dw) {
        float s = acc[dp * 3 + dw];
#pragma unroll
        for (int kw = 0; kw < 9; ++kw) s = fmaf(wr[kw], xr[OFF + 2 * dw + kw], s);
        acc[dp * 3 + dw] = s;
      }
    }
  }
}

__global__ __launch_bounds__(256) void primary_kernel(
    const float* __restrict__ x, const float* __restrict__ pw,
    const float* __restrict__ pb, float* __restrict__ u) {
  int ocg = blockIdx.x;  // 0..3
  int b   = blockIdx.y;  // 0..255
  __shared__ __align__(16) float xs[400];        // one ic image 20x20
  __shared__ __align__(16) float wsm[64 * 108];  // [oc][kh][12] padded
  int t = threadIdx.x;
  int oc = t & 63;
  int patch = t >> 6;  // 0..3 -> (ph0,pw0) in {0,3}^2
  int ph0 = (patch >> 1) * 3;
  float acc[9] = {0, 0, 0, 0, 0, 0, 0, 0, 0};
  for (int ic = 0; ic < 256; ++ic) {
    __syncthreads();
    for (int i = t; i < 400; i += 256) xs[i] = x[((size_t)b * 256 + ic) * 400 + i];
    for (int i = t; i < 5184; i += 256) {
      int o = i / 81, k = i % 81;
      int kh = k / 9, kw = k % 9;
      wsm[o * 108 + kh * 12 + kw] = pw[(((size_t)(ocg * 64 + o)) * 256 + ic) * 81 + k];
    }
    __syncthreads();
    if (patch & 1)
      primary_compute<1, 2>(xs, wsm, oc, ph0, acc);  // pw0=3
    else
      primary_compute<0, 0>(xs, wsm, oc, ph0, acc);  // pw0=0
  }
  int pw0 = (patch & 1) * 3;
  float bias = pb[ocg * 64 + oc];
#pragma unroll
  for (int dp = 0; dp < 3; ++dp)
#pragma unroll
    for (int dw = 0; dw < 3; ++dw)
      u[(size_t)b * 9216 + (ocg * 64 + oc) * 36 + (ph0 + dp) * 6 + (pw0 + dw)] =
          acc[dp * 3 + dw] + bias;
}

// ================================ squash ===================================
__global__ __launch_bounds__(256) void squash_kernel(float* __restrict__ u) {
  int g = blockIdx.x * 256 + threadIdx.x;  // 294912 groups of 8
  float* p = u + (size_t)g * 8;
  float4 v0 = reinterpret_cast<float4*>(p)[0];
  float4 v1 = reinterpret_cast<float4*>(p)[1];
  float sn = v0.x * v0.x + v0.y * v0.y + v0.z * v0.z + v0.w * v0.w +
             v1.x * v1.x + v1.y * v1.y + v1.z * v1.z + v1.w * v1.w;
  float f = sn / ((1.f + sn) * sqrtf(sn));
  v0.x *= f; v0.y *= f; v0.z *= f; v0.w *= f;
  v1.x *= f; v1.y *= f; v1.z *= f; v1.w *= f;
  reinterpret_cast<float4*>(p)[0] = v0;
  reinterpret_cast<float4*>(p)[1] = v1;
}

// ================================ helpers ==================================
__global__ void zero_kernel(float* __restrict__ p, int n) {
  int i = blockIdx.x * 256 + threadIdx.x;
  if (i < n) p[i] = 0.f;
}

// softmax over r (1152) per cls; bp layout [r][10]
__global__ __launch_bounds__(256) void softmax_c_kernel(const float* __restrict__ bp,
                                                        float* __restrict__ c) {
  int cls = blockIdx.x;
  int t = threadIdx.x;
  __shared__ float red[256];
  float m = -1e30f;
  for (int r = t; r < 1152; r += 256) m = fmaxf(m, bp[r * 10 + cls]);
  red[t] = m;
  __syncthreads();
  for (int s = 128; s > 0; s >>= 1) {
    if (t < s) red[t] = fmaxf(red[t], red[t + s]);
    __syncthreads();
  }
  m = red[0];
  __syncthreads();
  float sum = 0.f;
  for (int r = t; r < 1152; r += 256) sum += expf(bp[r * 10 + cls] - m);
  red[t] = sum;
  __syncthreads();
  for (int s = 128; s > 0; s >>= 1) {
    if (t < s) red[t] += red[t + s];
    __syncthreads();
  }
  float den = red[0];
  for (int r = t; r < 1152; r += 256) c[r * 10 + cls] = expf(bp[r * 10 + cls] - m) / den;
}

// WC[j] = W[j] * c[j/128]   (j/128 == r*10+cls)
__global__ __launch_bounds__(256) void wc_kernel(const float* __restrict__ W,
                                                 const float* __restrict__ c,
                                                 float* __restrict__ WC) {
  int j = blockIdx.x * 256 + threadIdx.x;
  if (j < 1474560) WC[j] = W[j] * c[j >> 7];
}

// s_part[ks][b][col] = sum over k-chunk of WC[k,col]*u[b,k]
// grid (5 colTiles, 4 bTiles, 8 kSplits), tile 64b x 32col x 1152k
__global__ __launch_bounds__(256) void s_gemm_kernel(const float* __restrict__ u,
                                                     const float* __restrict__ WC,
                                                     float* __restrict__ s_part) {
  int ct = blockIdx.x, bt = blockIdx.y, ks = blockIdx.z;
  __shared__ float u_s[64][32];
  __shared__ float w_s[32][33];
  int t = threadIdx.x;
  int c8 = t & 31, bq = t >> 5;  // col in tile; 8 b-rows per thread
  float acc[8] = {0, 0, 0, 0, 0, 0, 0, 0};
  int k0 = ks * 1152;
  for (int sc = 0; sc < 36; ++sc) {
    int kbase = k0 + sc * 32;
    __syncthreads();
    for (int q = t; q < 2048; q += 256) {
      int bb = q >> 5, kk = q & 31;
      u_s[bb][kk] = u[(size_t)(bt * 64 + bb) * 9216 + kbase + kk];
    }
    int rbase = kbase >> 3;
    for (int q = t; q < 1024; q += 256) {
      int r4 = q >> 8, rem = q & 255;
      int cc = rem >> 3, ie = rem & 7;
      w_s[r4 * 8 + ie][cc] = WC[(size_t)(rbase + r4) * 1280 + (ct * 32 + cc) * 8 + ie];
    }
    __syncthreads();
#pragma unroll
    for (int kk = 0; kk < 32; ++kk) {
      float wv = w_s[kk][c8];
#pragma unroll
      for (int m = 0; m < 8; ++m) acc[m] = fmaf(u_s[bq * 8 + m][kk], wv, acc[m]);
    }
  }
  for (int m = 0; m < 8; ++m)
    s_part[((size_t)ks * 256 + bt * 64 + bq * 8 + m) * 160 + ct * 32 + c8] = acc[m];
}

// v = f(s) with s = sum of 8 partials; optionally also write to d_out
__global__ __launch_bounds__(256) void reduce_v_kernel(const float* __restrict__ s_part,
                                                       float* __restrict__ v,
                                                       float* __restrict__ out,
                                                       int write_out) {
  int i = blockIdx.x * 256 + threadIdx.x;  // 40960
  float s = 0.f;
#pragma unroll
  for (int ks = 0; ks < 8; ++ks) s += s_part[ks * 40960 + i];
  float val = s * fabsf(s) / (1.f + s * s);
  v[i] = val;
  if (write_out) out[i] = val;
}

// T[k][col] = (1/256) sum_b u[b,k]*v[b,col]; grid (72 kTiles, 5 colTiles)
__global__ __launch_bounds__(256) void t_gemm_kernel(const float* __restrict__ u,
                                                     const float* __restrict__ v,
                                                     float* __restrict__ T) {
  int kt = blockIdx.x, ct = blockIdx.y;
  __shared__ float u_s[32][128];
  __shared__ float v_s[32][33];
  int t = threadIdx.x;
  int col = t & 31, kq = t >> 5;  // 16 k rows per thread
  float acc[16] = {0, 0, 0, 0, 0, 0, 0, 0, 0, 0, 0, 0, 0, 0, 0, 0};
  for (int b0 = 0; b0 < 256; b0 += 32) {
    __syncthreads();
    for (int q = t; q < 4096; q += 256) {
      int bb = q >> 7, kk = q & 127;
      u_s[bb][kk] = u[(size_t)(b0 + bb) * 9216 + kt * 128 + kk];
    }
    for (int q = t; q < 1024; q += 256) {
      int bb = q >> 5, cc = q & 31;
      v_s[bb][cc] = v[(b0 + bb) * 160 + ct * 32 + cc];
    }
    __syncthreads();
    for (int bb = 0; bb < 32; ++bb) {
      float vv = v_s[bb][col];
#pragma unroll
      for (int m = 0; m < 16; ++m)
        acc[m] = fmaf(u_s[bb][kq * 16 + m], vv, acc[m]);
    }
  }
  const float scl = 1.f / 256.f;
  for (int m = 0; m < 16; ++m)
    T[(size_t)(kt * 128 + kq * 16 + m) * 160 + ct * 32 + col] = acc[m] * scl;
}

// bp[r,cls] += sum_{o,i} W[r,cls,o,i] * T[(r,i),(cls,o)]
__global__ __launch_bounds__(256) void bp_update_kernel(const float* __restrict__ W,
                                                        const float* __restrict__ T,
                                                        float* __restrict__ bp) {
  int idx = blockIdx.x * 256 + threadIdx.x;  // 11520 = (r*10+cls)
  if (idx >= 11520) return;
  int r = idx / 10, cls = idx % 10;
  const float* wp = W + (size_t)idx * 128;  // contiguous o*8+i
  float s = 0.f;
#pragma unroll
  for (int o = 0; o < 16; ++o)
#pragma unroll
    for (int i = 0; i < 8; ++i)
      s = fmaf(wp[o * 8 + i], T[(size_t)(r * 8 + i) * 160 + cls * 16 + o], s);
  bp[idx] += s;
}

// class norms -> softmax over BATCH axis per class -> argmax -> mask + t
__global__ __launch_bounds__(256) void mask_kernel(const float* __restrict__ v,
                                                   float* __restrict__ masked,
                                                   float* __restrict__ tdec) {
  __shared__ float cls_s[256][10];
  __shared__ float colmax[10], colden[10];
  int t = threadIdx.x;  // = b
  float cl[10];
  for (int c = 0; c < 10; ++c) {
    float sum = 0.f;
    for (int o = 0; o < 16; ++o) {
      float q = v[t * 160 + c * 16 + o];
      sum += q * q;
    }
    cl[c] = sqrtf(sum);
    cls_s[t][c] = cl[c];
  }
  __syncthreads();
  if (t < 10) {
    float m = -1e30f;
    for (int b = 0; b < 256; ++b) m = fmaxf(m, cls_s[b][t]);
    float d = 0.f;
    for (int b = 0; b < 256; ++b) d += expf(cls_s[b][t] - m);
    colmax[t] = m;
    colden[t] = d;
  }
  __syncthreads();
  float best = -1e30f;
  int bi = 0;
  for (int c = 0; c < 10; ++c) {
    float p = expf(cl[c] - colmax[c]) / colden[c];
    if (p > best) { best = p; bi = c; }  // strict '>' keeps first max (jnp.argmax)
  }
  for (int c = 0; c < 10; ++c) masked[t * 10 + c] = (c == bi) ? 1.f : 0.f;
  for (int j = 0; j < 160; ++j)
    tdec[t * 160 + j] = ((j >> 4) == bi) ? v[t * 160 + j] : 0.f;
}

// out[b,j] = act(bias[j] + sum_k in[b,k]*w[j,k]); tile 16b x 64j, K%32==0
template <int ACT>  // 0 = relu, 1 = sigmoid
__global__ __launch_bounds__(256) void fc_kernel(const float* __restrict__ in,
                                                 const float* __restrict__ w,
                                                 const float* __restrict__ bias,
                                                 float* __restrict__ out, int K, int N) {
  int jt = blockIdx.x, bt = blockIdx.y;
  __shared__ float in_s[16][33];
  __shared__ float w_s[64][33];
  int t = threadIdx.x;
  int jl = t & 63, bq = t >> 6;  // 4 b-rows per thread
  float acc[4] = {0, 0, 0, 0};
  for (int k0 = 0; k0 < K; k0 += 32) {
    __syncthreads();
    for (int q = t; q < 512; q += 256) {
      int bb = q >> 5, kk = q & 31;
      in_s[bb][kk] = in[(size_t)(bt * 16 + bb) * K + k0 + kk];
    }
    for (int q = t; q < 2048; q += 256) {
      int jj = q >> 5, kk = q & 31;
      int jg = jt * 64 + jj;
      w_s[jj][kk] = (jg < N) ? w[(size_t)jg * K + k0 + kk] : 0.f;
    }
    __syncthreads();
#pragma unroll
    for (int kk = 0; kk < 32; ++kk) {
      float wv = w_s[jl][kk];
#pragma unroll
      for (int m = 0; m < 4; ++m) acc[m] = fmaf(in_s[bq * 4 + m][kk], wv, acc[m]);
    }
  }
  int jg = jt * 64 + jl;
  if (jg < N) {
    float bv = bias[jg];
    for (int m = 0; m < 4; ++m) {
      float r = acc[m] + bv;
      if (ACT == 0)
        r = fmaxf(r, 0.f);
      else
        r = 1.f / (1.f + expf(-r));
      out[(size_t)(bt * 16 + bq * 4 + m) * N + jg] = r;
    }
  }
}

// ===========================================================================
extern "C" void kernel_launch(void* const* d_in, const int* in_sizes, int n_in,
                              void* d_out, int out_size, void* d_ws, size_t ws_size,
                              hipStream_t stream) {
  const float* data  = (const float*)d_in[0];
  const float* convw = (const float*)d_in[1];
  const float* convb = (const float*)d_in[2];
  const float* pcw   = (const float*)d_in[3];
  const float* pcb   = (const float*)d_in[4];
  const float* W     = (const float*)d_in[5];
  const float* w1    = (const float*)d_in[6];
  const float* b1    = (const float*)d_in[7];
  const float* w2    = (const float*)d_in[8];
  const float* b2    = (const float*)d_in[9];
  const float* w3    = (const float*)d_in[10];
  const float* b3    = (const float*)d_in[11];
  float* out = (float*)d_out;

  char* wsb = (char*)d_ws;
  size_t off = 0;
  auto alloc = [&](size_t nfloats) {
    float* p = (float*)(wsb + off);
    off += nfloats * sizeof(float);
    return p;
  };
  float* x      = alloc(26214400);  // (256,256,20,20)
  float* u      = alloc(2359296);   // (256,9216)
  float* v      = alloc(40960);     // (256,160)
  float* s_part = alloc(8 * 40960);
  float* bp     = alloc(11520);     // (1152,10)
  float* c      = alloc(11520);
  float* WC     = alloc(1474560);   // c*W
  float* T      = alloc(1474560);   // (9216,160)
  float* tdec   = alloc(40960);
  float* h1     = alloc(131072);
  float* h2     = alloc(262144);
  if (ws_size < off) return;  // insufficient workspace -> visible failure

  conv1_kernel<<<dim3(4, 256), 256, 0, stream>>>(data, convw, convb, x);
  primary_kernel<<<dim3(4, 256), 256, 0, stream>>>(x, pcw, pcb, u);
  squash_kernel<<<1152, 256, 0, stream>>>(u);
  zero_kernel<<<45, 256, 0, stream>>>(bp, 11520);

  for (int it = 0; it < 3; ++it) {
    softmax_c_kernel<<<10, 256, 0, stream>>>(bp, c);
    wc_kernel<<<5760, 256, 0, stream>>>(W, c, WC);
    s_gemm_kernel<<<dim3(5, 4, 8), 256, 0, stream>>>(u, WC, s_part);
    reduce_v_kernel<<<160, 256, 0, stream>>>(s_part, v, out, it == 2 ? 1 : 0);
    if (it < 2) {
      t_gemm_kernel<<<dim3(72, 5), 256, 0, stream>>>(u, v, T);
      bp_update_kernel<<<45, 256, 0, stream>>>(W, T, bp);
    }
  }

  mask_kernel<<<1, 256, 0, stream>>>(v, out + 241664, tdec);
  fc_kernel<0><<<dim3(8, 16), 256, 0, stream>>>(tdec, w1, b1, h1, 160, 512);
  fc_kernel<0><<<dim3(16, 16), 256, 0, stream>>>(h1, w2, b2, h2, 512, 1024);
  fc_kernel<1><<<dim3(13, 16), 256, 0, stream>>>(h2, w3, b3, out + 40960, 1024, 784);
}

// Round 2
// 1559.468 us; speedup vs baseline: 2.9484x; 2.9484x over previous
//
#include <hip/hip_runtime.h>
#include <math.h>

typedef __attribute__((ext_vector_type(8))) short short8;
typedef __attribute__((ext_vector_type(16))) float f32x16;

static __device__ __forceinline__ unsigned short f2bf(float f) {
  unsigned int u = __float_as_uint(f);
  u += 0x7FFF + ((u >> 16) & 1);  // RNE
  return (unsigned short)(u >> 16);
}
static __device__ __forceinline__ float bf2f(unsigned short h) {
  return __uint_as_float(((unsigned int)h) << 16);
}

__device__ __forceinline__ void gl2lds16(const void* g, void* l) {
  __builtin_amdgcn_global_load_lds(
      (const __attribute__((address_space(1))) unsigned int*)g,
      (__attribute__((address_space(3))) unsigned int*)l, 16, 0, 0);
}

// ============================ conv1 (1->256, 9x9, s1) ======================
__global__ __launch_bounds__(256) void conv1_kernel(
    const float* __restrict__ data, const float* __restrict__ cw,
    const float* __restrict__ cb, float* __restrict__ x) {
  int ocg = blockIdx.x;   // 0..3, 64 oc each
  int b   = blockIdx.y;   // 0..255
  __shared__ __align__(16) float img[784];       // 28x28
  __shared__ __align__(16) float wsm[64 * 108];  // [oc][kh][12] padded rows
  int t = threadIdx.x;
  for (int i = t; i < 784; i += 256) img[i] = data[b * 784 + i];
  for (int i = t; i < 64 * 81; i += 256) {
    int oc = i / 81, k = i % 81;
    int kh = k / 9, kw = k % 9;
    wsm[oc * 108 + kh * 12 + kw] = cw[(ocg * 64 + oc) * 81 + k];
  }
  __syncthreads();
  for (int idx = t; idx < 6400; idx += 256) {
    int oc = idx / 100, q = idx % 100;
    int ph = q / 5, pw0 = (q % 5) * 4;
    float a0 = 0.f, a1 = 0.f, a2 = 0.f, a3 = 0.f;
#pragma unroll
    for (int kh = 0; kh < 9; ++kh) {
      const float4* ir4 = reinterpret_cast<const float4*>(&img[(ph + kh) * 28 + pw0]);
      float4 i0 = ir4[0], i1 = ir4[1], i2 = ir4[2];
      float im[12] = {i0.x, i0.y, i0.z, i0.w, i1.x, i1.y, i1.z, i1.w,
                      i2.x, i2.y, i2.z, i2.w};
      const float4* wr4 = reinterpret_cast<const float4*>(&wsm[oc * 108 + kh * 12]);
      float4 w0 = wr4[0], w1 = wr4[1], w2 = wr4[2];
      float wr[9] = {w0.x, w0.y, w0.z, w0.w, w1.x, w1.y, w1.z, w1.w, w2.x};
#pragma unroll
      for (int kw = 0; kw < 9; ++kw) {
        a0 = fmaf(wr[kw], im[kw + 0], a0);
        a1 = fmaf(wr[kw], im[kw + 1], a1);
        a2 = fmaf(wr[kw], im[kw + 2], a2);
        a3 = fmaf(wr[kw], im[kw + 3], a3);
      }
    }
    float bias = cb[ocg * 64 + oc];
    float* xp = &x[((size_t)b * 256 + ocg * 64 + oc) * 400 + ph * 20 + pw0];
    xp[0] = fmaxf(a0 + bias, 0.f);
    xp[1] = fmaxf(a1 + bias, 0.f);
    xp[2] = fmaxf(a2 + bias, 0.f);
    xp[3] = fmaxf(a3 + bias, 0.f);
  }
}

// ============ x (b,ic,20,20) fp32 -> xT[b][row][col][ic] bf16 hi/lo ========
__global__ __launch_bounds__(256) void xt_kernel(const float* __restrict__ x,
                                                 unsigned short* __restrict__ xh,
                                                 unsigned short* __restrict__ xl) {
  int bt = blockIdx.x;  // ic_t*4 + rc_t
  int b = blockIdx.y;
  int ic0 = (bt >> 2) * 64, rc0 = (bt & 3) * 100;
  __shared__ float raw[64][105];
  int t = threadIdx.x;
  for (int i = t; i < 6400; i += 256) {
    int icl = i / 100, rc = i - icl * 100;
    raw[icl][rc] = x[((size_t)(b * 256 + ic0 + icl)) * 400 + rc0 + rc];
  }
  __syncthreads();
  for (int i = t; i < 6400; i += 256) {
    int icl = i & 63, rc = i >> 6;
    float v = raw[icl][rc];
    unsigned short h = f2bf(v);
    float lo = v - bf2f(h);
    size_t o = ((size_t)b * 400 + rc0 + rc) * 256 + ic0 + icl;
    xh[o] = h;
    xl[o] = f2bf(lo);
  }
}

// === pw (256oc,256ic,9,9) fp32 -> A-fragment layout [kc][ocg][lane][8] =====
// k = kh*2304 + kw*256 + ic ; lane holds A[oc=ocg*32+(l&31)][k=kc*16+(l>>5)*8+e]
__global__ __launch_bounds__(256) void wcvt_kernel(const float* __restrict__ pw,
                                                   unsigned short* __restrict__ ah,
                                                   unsigned short* __restrict__ al) {
  int tid = blockIdx.x * 256 + threadIdx.x;  // 663552 = 1296*8*64
  int l = tid & 63;
  int ocg = (tid >> 6) & 7;
  int kc = tid >> 9;
  int oc = ocg * 32 + (l & 31);
  size_t obase = (size_t)tid * 8;
#pragma unroll
  for (int e = 0; e < 8; ++e) {
    int k = kc * 16 + ((l >> 5) << 3) + e;
    int kh = k / 2304;
    int r = k - kh * 2304;
    int kw = r >> 8, ic = r & 255;
    float v = pw[((size_t)oc * 256 + ic) * 81 + kh * 9 + kw];
    unsigned short h = f2bf(v);
    ah[obase + e] = h;
    al[obase + e] = f2bf(v - bf2f(h));
  }
}

// ================= primary conv as MFMA implicit GEMM ======================
// C[oc 256][n 9216] partials; grid (72 nTiles, 2 mTiles, 8 kSplits)
__global__ __launch_bounds__(256, 2) void pgemm_kernel(
    const unsigned short* __restrict__ Agh, const unsigned short* __restrict__ Agl,
    const unsigned short* __restrict__ Xh, const unsigned short* __restrict__ Xl,
    float* __restrict__ part) {
  __shared__ __align__(16) unsigned short sA[2][2][2][4][64][8];  // buf,split,kl,ocg,lane,e
  __shared__ __align__(16) unsigned short sB[2][2][2][4][64][8];  // buf,split,kl,c,lane,e
  const int t = threadIdx.x;
  const int l = t & 63;
  const int w = t >> 6;
  const int wm = w >> 1, wn = w & 1;
  const int m0 = blockIdx.y;
  const int n0 = blockIdx.x * 128;
  const int zk = blockIdx.z;
  const int kcb = zk * 162;  // 162 kc-chunks (of 16 k) per split

  // B staging: wave w stages n-chunk c=w; per-lane base into xT
  int n = n0 + w * 32 + (l & 31);
  int b_ = n / 36;
  int pos = n - b_ * 36;
  int ph = pos / 6, pww = pos - ph * 6;
  size_t pbase = (((size_t)b_ * 20 + 2 * ph) * 20 + 2 * pww) * 256 + ((l >> 5) << 3);

  // A staging: wave w handles (split sw, kl klw), 4 ocg segments
  const int sw = w >> 1, klw = w & 1;
  const unsigned short* Asrc = sw ? Agl : Agh;
  const size_t aoff0 = (((size_t)(kcb + klw) * 8 + m0 * 4) * 64 + l) * 8;

  f32x16 acc[2][2];
#pragma unroll
  for (int j = 0; j < 2; ++j)
#pragma unroll
    for (int j2 = 0; j2 < 2; ++j2)
#pragma unroll
      for (int r = 0; r < 16; ++r) acc[j][j2][r] = 0.f;

  auto koff = [](int kc) {
    int kh = (unsigned)kc / 144u;
    int r = kc - kh * 144;
    return ((kh * 20 + (r >> 4)) << 8) + ((r & 15) << 4);
  };
  auto stage = [&](int buf, int step) {
    size_t ao = aoff0 + (size_t)step * 8192;
#pragma unroll
    for (int j = 0; j < 4; ++j)
      gl2lds16(Asrc + ao + j * 512, &sA[buf][sw][klw][j][0][0]);
    int kc0 = kcb + 2 * step;
    int o0 = koff(kc0), o1 = koff(kc0 + 1);
    gl2lds16(Xh + pbase + o0, &sB[buf][0][0][w][0][0]);
    gl2lds16(Xh + pbase + o1, &sB[buf][0][1][w][0][0]);
    gl2lds16(Xl + pbase + o0, &sB[buf][1][0][w][0][0]);
    gl2lds16(Xl + pbase + o1, &sB[buf][1][1][w][0][0]);
  };

  stage(0, 0);
  __syncthreads();
  int buf = 0;
  for (int step = 0; step < 81; ++step) {
    if (step + 1 < 81) stage(buf ^ 1, step + 1);
#pragma unroll
    for (int kl = 0; kl < 2; ++kl) {
      short8 a0h = *(const short8*)&sA[buf][0][kl][wm * 2 + 0][l][0];
      short8 a1h = *(const short8*)&sA[buf][0][kl][wm * 2 + 1][l][0];
      short8 a0l = *(const short8*)&sA[buf][1][kl][wm * 2 + 0][l][0];
      short8 a1l = *(const short8*)&sA[buf][1][kl][wm * 2 + 1][l][0];
      short8 b0h = *(const short8*)&sB[buf][0][kl][wn * 2 + 0][l][0];
      short8 b1h = *(const short8*)&sB[buf][0][kl][wn * 2 + 1][l][0];
      short8 b0l = *(const short8*)&sB[buf][1][kl][wn * 2 + 0][l][0];
      short8 b1l = *(const short8*)&sB[buf][1][kl][wn * 2 + 1][l][0];
      acc[0][0] = __builtin_amdgcn_mfma_f32_32x32x16_bf16(a0h, b0h, acc[0][0], 0, 0, 0);
      acc[0][0] = __builtin_amdgcn_mfma_f32_32x32x16_bf16(a0h, b0l, acc[0][0], 0, 0, 0);
      acc[0][0] = __builtin_amdgcn_mfma_f32_32x32x16_bf16(a0l, b0h, acc[0][0], 0, 0, 0);
      acc[0][1] = __builtin_amdgcn_mfma_f32_32x32x16_bf16(a0h, b1h, acc[0][1], 0, 0, 0);
      acc[0][1] = __builtin_amdgcn_mfma_f32_32x32x16_bf16(a0h, b1l, acc[0][1], 0, 0, 0);
      acc[0][1] = __builtin_amdgcn_mfma_f32_32x32x16_bf16(a0l, b1h, acc[0][1], 0, 0, 0);
      acc[1][0] = __builtin_amdgcn_mfma_f32_32x32x16_bf16(a1h, b0h, acc[1][0], 0, 0, 0);
      acc[1][0] = __builtin_amdgcn_mfma_f32_32x32x16_bf16(a1h, b0l, acc[1][0], 0, 0, 0);
      acc[1][0] = __builtin_amdgcn_mfma_f32_32x32x16_bf16(a1l, b0h, acc[1][0], 0, 0, 0);
      acc[1][1] = __builtin_amdgcn_mfma_f32_32x32x16_bf16(a1h, b1h, acc[1][1], 0, 0, 0);
      acc[1][1] = __builtin_amdgcn_mfma_f32_32x32x16_bf16(a1h, b1l, acc[1][1], 0, 0, 0);
      acc[1][1] = __builtin_amdgcn_mfma_f32_32x32x16_bf16(a1l, b1h, acc[1][1], 0, 0, 0);
    }
    __syncthreads();
    buf ^= 1;
  }

  // C/D layout (32x32): col = lane&31, row = (reg&3)+8*(reg>>2)+4*(lane>>5)
#pragma unroll
  for (int j = 0; j < 2; ++j)
#pragma unroll
    for (int j2 = 0; j2 < 2; ++j2) {
      int ocb = m0 * 128 + wm * 64 + j * 32;
      int nb = n0 + wn * 64 + j2 * 32 + (l & 31);
#pragma unroll
      for (int r = 0; r < 16; ++r) {
        int row = (r & 3) + 8 * (r >> 2) + ((l >> 5) << 2);
        part[((size_t)(zk * 256 + ocb + row)) * 9216 + nb] = acc[j][j2][r];
      }
    }
}

// === u[b][oc*36+pos] = bias[oc] + sum_z part[z][oc][n], n = b*36+pos ========
__global__ __launch_bounds__(256) void ured_kernel(const float* __restrict__ part,
                                                   const float* __restrict__ pb,
                                                   float* __restrict__ u) {
  int tid = blockIdx.x * 256 + threadIdx.x;  // 2359296
  int oc = tid / 9216;
  int n = tid - oc * 9216;
  float s = pb[oc];
#pragma unroll
  for (int z = 0; z < 8; ++z) s += part[((size_t)z * 256 + oc) * 9216 + n];
  int b = n / 36;
  int pos = n - b * 36;
  u[(size_t)b * 9216 + oc * 36 + pos] = s;
}

// ================================ squash ===================================
__global__ __launch_bounds__(256) void squash_kernel(float* __restrict__ u) {
  int g = blockIdx.x * 256 + threadIdx.x;
  float* p = u + (size_t)g * 8;
  float4 v0 = reinterpret_cast<float4*>(p)[0];
  float4 v1 = reinterpret_cast<float4*>(p)[1];
  float sn = v0.x * v0.x + v0.y * v0.y + v0.z * v0.z + v0.w * v0.w +
             v1.x * v1.x + v1.y * v1.y + v1.z * v1.z + v1.w * v1.w;
  float f = sn / ((1.f + sn) * sqrtf(sn));
  v0.x *= f; v0.y *= f; v0.z *= f; v0.w *= f;
  v1.x *= f; v1.y *= f; v1.z *= f; v1.w *= f;
  reinterpret_cast<float4*>(p)[0] = v0;
  reinterpret_cast<float4*>(p)[1] = v1;
}

// ================================ helpers ==================================
__global__ void zero_kernel(float* __restrict__ p, int n) {
  int i = blockIdx.x * 256 + threadIdx.x;
  if (i < n) p[i] = 0.f;
}

__global__ __launch_bounds__(256) void softmax_c_kernel(const float* __restrict__ bp,
                                                        float* __restrict__ c) {
  int cls = blockIdx.x;
  int t = threadIdx.x;
  __shared__ float red[256];
  float m = -1e30f;
  for (int r = t; r < 1152; r += 256) m = fmaxf(m, bp[r * 10 + cls]);
  red[t] = m;
  __syncthreads();
  for (int s = 128; s > 0; s >>= 1) {
    if (t < s) red[t] = fmaxf(red[t], red[t + s]);
    __syncthreads();
  }
  m = red[0];
  __syncthreads();
  float sum = 0.f;
  for (int r = t; r < 1152; r += 256) sum += expf(bp[r * 10 + cls] - m);
  red[t] = sum;
  __syncthreads();
  for (int s = 128; s > 0; s >>= 1) {
    if (t < s) red[t] += red[t + s];
    __syncthreads();
  }
  float den = red[0];
  for (int r = t; r < 1152; r += 256) c[r * 10 + cls] = expf(bp[r * 10 + cls] - m) / den;
}

__global__ __launch_bounds__(256) void wc_kernel(const float* __restrict__ W,
                                                 const float* __restrict__ c,
                                                 float* __restrict__ WC) {
  int j = blockIdx.x * 256 + threadIdx.x;
  if (j < 1474560) WC[j] = W[j] * c[j >> 7];
}

__global__ __launch_bounds__(256) void s_gemm_kernel(const float* __restrict__ u,
                                                     const float* __restrict__ WC,
                                                     float* __restrict__ s_part) {
  int ct = blockIdx.x, bt = blockIdx.y, ks = blockIdx.z;
  __shared__ float u_s[64][32];
  __shared__ float w_s[32][33];
  int t = threadIdx.x;
  int c8 = t & 31, bq = t >> 5;
  float acc[8] = {0, 0, 0, 0, 0, 0, 0, 0};
  int k0 = ks * 1152;
  for (int sc = 0; sc < 36; ++sc) {
    int kbase = k0 + sc * 32;
    __syncthreads();
    for (int q = t; q < 2048; q += 256) {
      int bb = q >> 5, kk = q & 31;
      u_s[bb][kk] = u[(size_t)(bt * 64 + bb) * 9216 + kbase + kk];
    }
    int rbase = kbase >> 3;
    for (int q = t; q < 1024; q += 256) {
      int r4 = q >> 8, rem = q & 255;
      int cc = rem >> 3, ie = rem & 7;
      w_s[r4 * 8 + ie][cc] = WC[(size_t)(rbase + r4) * 1280 + (ct * 32 + cc) * 8 + ie];
    }
    __syncthreads();
#pragma unroll
    for (int kk = 0; kk < 32; ++kk) {
      float wv = w_s[kk][c8];
#pragma unroll
      for (int m = 0; m < 8; ++m) acc[m] = fmaf(u_s[bq * 8 + m][kk], wv, acc[m]);
    }
  }
  for (int m = 0; m < 8; ++m)
    s_part[((size_t)ks * 256 + bt * 64 + bq * 8 + m) * 160 + ct * 32 + c8] = acc[m];
}

__global__ __launch_bounds__(256) void reduce_v_kernel(const float* __restrict__ s_part,
                                                       float* __restrict__ v,
                                                       float* __restrict__ out,
                                                       int write_out) {
  int i = blockIdx.x * 256 + threadIdx.x;
  float s = 0.f;
#pragma unroll
  for (int ks = 0; ks < 8; ++ks) s += s_part[ks * 40960 + i];
  float val = s * fabsf(s) / (1.f + s * s);
  v[i] = val;
  if (write_out) out[i] = val;
}

__global__ __launch_bounds__(256) void t_gemm_kernel(const float* __restrict__ u,
                                                     const float* __restrict__ v,
                                                     float* __restrict__ T) {
  int kt = blockIdx.x, ct = blockIdx.y;
  __shared__ float u_s[32][128];
  __shared__ float v_s[32][33];
  int t = threadIdx.x;
  int col = t & 31, kq = t >> 5;
  float acc[16] = {0, 0, 0, 0, 0, 0, 0, 0, 0, 0, 0, 0, 0, 0, 0, 0};
  for (int b0 = 0; b0 < 256; b0 += 32) {
    __syncthreads();
    for (int q = t; q < 4096; q += 256) {
      int bb = q >> 7, kk = q & 127;
      u_s[bb][kk] = u[(size_t)(b0 + bb) * 9216 + kt * 128 + kk];
    }
    for (int q = t; q < 1024; q += 256) {
      int bb = q >> 5, cc = q & 31;
      v_s[bb][cc] = v[(b0 + bb) * 160 + ct * 32 + cc];
    }
    __syncthreads();
    for (int bb = 0; bb < 32; ++bb) {
      float vv = v_s[bb][col];
#pragma unroll
      for (int m = 0; m < 16; ++m)
        acc[m] = fmaf(u_s[bb][kq * 16 + m], vv, acc[m]);
    }
  }
  const float scl = 1.f / 256.f;
  for (int m = 0; m < 16; ++m)
    T[(size_t)(kt * 128 + kq * 16 + m) * 160 + ct * 32 + col] = acc[m] * scl;
}

__global__ __launch_bounds__(256) void bp_update_kernel(const float* __restrict__ W,
                                                        const float* __restrict__ T,
                                                        float* __restrict__ bp) {
  int idx = blockIdx.x * 256 + threadIdx.x;
  if (idx >= 11520) return;
  int r = idx / 10, cls = idx % 10;
  const float* wp = W + (size_t)idx * 128;
  float s = 0.f;
#pragma unroll
  for (int o = 0; o < 16; ++o)
#pragma unroll
    for (int i = 0; i < 8; ++i)
      s = fmaf(wp[o * 8 + i], T[(size_t)(r * 8 + i) * 160 + cls * 16 + o], s);
  bp[idx] += s;
}

__global__ __launch_bounds__(256) void mask_kernel(const float* __restrict__ v,
                                                   float* __restrict__ masked,
                                                   float* __restrict__ tdec) {
  __shared__ float cls_s[256][10];
  __shared__ float colmax[10], colden[10];
  int t = threadIdx.x;
  float cl[10];
  for (int c = 0; c < 10; ++c) {
    float sum = 0.f;
    for (int o = 0; o < 16; ++o) {
      float q = v[t * 160 + c * 16 + o];
      sum += q * q;
    }
    cl[c] = sqrtf(sum);
    cls_s[t][c] = cl[c];
  }
  __syncthreads();
  if (t < 10) {
    float m = -1e30f;
    for (int b = 0; b < 256; ++b) m = fmaxf(m, cls_s[b][t]);
    float d = 0.f;
    for (int b = 0; b < 256; ++b) d += expf(cls_s[b][t] - m);
    colmax[t] = m;
    colden[t] = d;
  }
  __syncthreads();
  float best = -1e30f;
  int bi = 0;
  for (int c = 0; c < 10; ++c) {
    float p = expf(cl[c] - colmax[c]) / colden[c];
    if (p > best) { best = p; bi = c; }
  }
  for (int c = 0; c < 10; ++c) masked[t * 10 + c] = (c == bi) ? 1.f : 0.f;
  for (int j = 0; j < 160; ++j)
    tdec[t * 160 + j] = ((j >> 4) == bi) ? v[t * 160 + j] : 0.f;
}

template <int ACT>
__global__ __launch_bounds__(256) void fc_kernel(const float* __restrict__ in,
                                                 const float* __restrict__ w,
                                                 const float* __restrict__ bias,
                                                 float* __restrict__ out, int K, int N) {
  int jt = blockIdx.x, bt = blockIdx.y;
  __shared__ float in_s[16][33];
  __shared__ float w_s[64][33];
  int t = threadIdx.x;
  int jl = t & 63, bq = t >> 6;
  float acc[4] = {0, 0, 0, 0};
  for (int k0 = 0; k0 < K; k0 += 32) {
    __syncthreads();
    for (int q = t; q < 512; q += 256) {
      int bb = q >> 5, kk = q & 31;
      in_s[bb][kk] = in[(size_t)(bt * 16 + bb) * K + k0 + kk];
    }
    for (int q = t; q < 2048; q += 256) {
      int jj = q >> 5, kk = q & 31;
      int jg = jt * 64 + jj;
      w_s[jj][kk] = (jg < N) ? w[(size_t)jg * K + k0 + kk] : 0.f;
    }
    __syncthreads();
#pragma unroll
    for (int kk = 0; kk < 32; ++kk) {
      float wv = w_s[jl][kk];
#pragma unroll
      for (int m = 0; m < 4; ++m) acc[m] = fmaf(in_s[bq * 4 + m][kk], wv, acc[m]);
    }
  }
  int jg = jt * 64 + jl;
  if (jg < N) {
    float bv = bias[jg];
    for (int m = 0; m < 4; ++m) {
      float r = acc[m] + bv;
      if (ACT == 0)
        r = fmaxf(r, 0.f);
      else
        r = 1.f / (1.f + expf(-r));
      out[(size_t)(bt * 16 + bq * 4 + m) * N + jg] = r;
    }
  }
}

// ===========================================================================
extern "C" void kernel_launch(void* const* d_in, const int* in_sizes, int n_in,
                              void* d_out, int out_size, void* d_ws, size_t ws_size,
                              hipStream_t stream) {
  const float* data  = (const float*)d_in[0];
  const float* convw = (const float*)d_in[1];
  const float* convb = (const float*)d_in[2];
  const float* pcw   = (const float*)d_in[3];
  const float* pcb   = (const float*)d_in[4];
  const float* W     = (const float*)d_in[5];
  const float* w1    = (const float*)d_in[6];
  const float* b1    = (const float*)d_in[7];
  const float* w2    = (const float*)d_in[8];
  const float* b2    = (const float*)d_in[9];
  const float* w3    = (const float*)d_in[10];
  const float* b3    = (const float*)d_in[11];
  float* out = (float*)d_out;

  char* wsb = (char*)d_ws;
  size_t off = 0;
  auto allocb = [&](size_t bytes) {
    void* p = wsb + off;
    off += (bytes + 255) & ~(size_t)255;
    return p;
  };
  float* x      = (float*)allocb(104857600);  // (256,256,20,20) fp32; later reused as pgemm partials
  float* u      = (float*)allocb(9437184);    // (256,9216)
  float* v      = (float*)allocb(163840);
  float* s_part = (float*)allocb(1310720);
  float* bp     = (float*)allocb(46080);
  float* c      = (float*)allocb(46080);
  float* WC     = (float*)allocb(5898240);
  float* T      = (float*)allocb(5898240);
  float* tdec   = (float*)allocb(163840);
  float* h1     = (float*)allocb(524288);
  float* h2     = (float*)allocb(1048576);
  unsigned short* xTh = (unsigned short*)allocb(52428800);  // [b][20][20][256] bf16 hi
  unsigned short* xTl = (unsigned short*)allocb(52428800);  // lo
  unsigned short* Agh = (unsigned short*)allocb(10616832);  // A fragments hi
  unsigned short* Agl = (unsigned short*)allocb(10616832);  // A fragments lo
  float* part = x;  // 8*256*9216 fp32 = 75.5 MB, overlays dead x
  if (ws_size < off) return;

  conv1_kernel<<<dim3(4, 256), 256, 0, stream>>>(data, convw, convb, x);
  xt_kernel<<<dim3(16, 256), 256, 0, stream>>>(x, xTh, xTl);
  wcvt_kernel<<<2592, 256, 0, stream>>>(pcw, Agh, Agl);
  pgemm_kernel<<<dim3(72, 2, 8), 256, 0, stream>>>(Agh, Agl, xTh, xTl, part);
  ured_kernel<<<9216, 256, 0, stream>>>(part, pcb, u);
  squash_kernel<<<1152, 256, 0, stream>>>(u);
  zero_kernel<<<45, 256, 0, stream>>>(bp, 11520);

  for (int it = 0; it < 3; ++it) {
    softmax_c_kernel<<<10, 256, 0, stream>>>(bp, c);
    wc_kernel<<<5760, 256, 0, stream>>>(W, c, WC);
    s_gemm_kernel<<<dim3(5, 4, 8), 256, 0, stream>>>(u, WC, s_part);
    reduce_v_kernel<<<160, 256, 0, stream>>>(s_part, v, out, it == 2 ? 1 : 0);
    if (it < 2) {
      t_gemm_kernel<<<dim3(72, 5), 256, 0, stream>>>(u, v, T);
      bp_update_kernel<<<45, 256, 0, stream>>>(W, T, bp);
    }
  }

  mask_kernel<<<1, 256, 0, stream>>>(v, out + 241664, tdec);
  fc_kernel<0><<<dim3(8, 16), 256, 0, stream>>>(tdec, w1, b1, h1, 160, 512);
  fc_kernel<0><<<dim3(16, 16), 256, 0, stream>>>(h1, w2, b2, h2, 512, 1024);
  fc_kernel<1><<<dim3(13, 16), 256, 0, stream>>>(h2, w3, b3, out + 40960, 1024, 784);
}

// Round 3
// 997.556 us; speedup vs baseline: 4.6092x; 1.5633x over previous
//
#include <hip/hip_runtime.h>
#include <math.h>

typedef __attribute__((ext_vector_type(8))) short short8;
typedef __attribute__((ext_vector_type(16))) float f32x16;
typedef unsigned short ushort_t;

static __device__ __forceinline__ unsigned short f2bf(float f) {
  unsigned int u = __float_as_uint(f);
  u += 0x7FFF + ((u >> 16) & 1);  // RNE
  return (unsigned short)(u >> 16);
}
static __device__ __forceinline__ float bf2f(unsigned short h) {
  return __uint_as_float(((unsigned int)h) << 16);
}

__device__ __forceinline__ void gl2lds16(const void* g, void* l) {
  __builtin_amdgcn_global_load_lds(
      (const __attribute__((address_space(1))) unsigned int*)g,
      (__attribute__((address_space(3))) unsigned int*)l, 16, 0, 0);
}

// ======= conv1 A: conv_w (256,81) -> frag layout [kc 9][ocg 8][64][8] ======
// k = kh*16 + kwp (kwp 0..15, zero-pad kwp>=9)
__global__ __launch_bounds__(256) void acvt_kernel(const float* __restrict__ cw,
                                                   ushort_t* __restrict__ ah,
                                                   ushort_t* __restrict__ al) {
  int tid = blockIdx.x * 256 + threadIdx.x;  // 4608 = 9*8*64
  if (tid >= 4608) return;
  int l = tid & 63;
  int ocg = (tid >> 6) & 7;
  int kc = tid >> 9;  // = kh
  int oc = ocg * 32 + (l & 31);
  size_t obase = (size_t)tid * 8;
#pragma unroll
  for (int e = 0; e < 8; ++e) {
    int kwp = ((l >> 5) << 3) + e;
    float v = (kwp < 9) ? cw[oc * 81 + kc * 9 + kwp] : 0.f;
    unsigned short h = f2bf(v);
    ah[obase + e] = h;
    al[obase + e] = f2bf(v - bf2f(h));
  }
}

// ======= conv1 B: im2col to frag layout [kc 9][n 102400][half 2][8] ========
__global__ __launch_bounds__(256) void im2col_kernel(const float* __restrict__ data,
                                                     ushort_t* __restrict__ bh,
                                                     ushort_t* __restrict__ bl) {
  int idx16 = blockIdx.x * 256 + threadIdx.x;  // 1843200
  int kc = idx16 / 204800;
  int rem = idx16 - kc * 204800;
  int n = rem >> 1, half = rem & 1;
  int b = n / 400;
  int pos = n - b * 400;
  int ph = pos / 20, pw = pos - ph * 20;
  const float* src = data + b * 784 + (ph + kc) * 28 + pw + half * 8;
  size_t obase = (size_t)idx16 * 8;
#pragma unroll
  for (int e = 0; e < 8; ++e) {
    int kwp = half * 8 + e;
    float v = (kwp < 9) ? src[e] : 0.f;
    unsigned short h = f2bf(v);
    bh[obase + e] = h;
    bl[obase + e] = f2bf(v - bf2f(h));
  }
}

// ====== conv1 as MFMA GEMM: C[256 oc][n] -> bias+relu -> xT bf16 hi/lo =====
struct StageC {
  ushort_t ah[2][8][64][8];
  ushort_t al[2][8][64][8];
  ushort_t bh[2][2][64][8];
  ushort_t bl[2][2][64][8];
};
__global__ __launch_bounds__(256, 2) void cgemm_kernel(
    const ushort_t* __restrict__ Afh, const ushort_t* __restrict__ Afl,
    const ushort_t* __restrict__ Bfh, const ushort_t* __restrict__ Bfl,
    const float* __restrict__ cb, ushort_t* __restrict__ xTh,
    ushort_t* __restrict__ xTl) {
  __shared__ __align__(16) union { StageC st; float ep[256][33]; } L;
  const int t = threadIdx.x;
  const int l = t & 63;
  const int w = t >> 6;  // wave = oc-group of 64
  const int n0 = blockIdx.x * 64;

  f32x16 acc[2][2];
#pragma unroll
  for (int j = 0; j < 2; ++j)
#pragma unroll
    for (int nc = 0; nc < 2; ++nc)
#pragma unroll
      for (int r = 0; r < 16; ++r) acc[j][nc][r] = 0.f;

  auto stage = [&](int buf, int kc) {
#pragma unroll
    for (int q5 = 0; q5 < 5; ++q5) {
      int q = w * 5 + q5;
      if (q < 16) {
        int sp = q >> 3, ocg = q & 7;
        const ushort_t* src = (sp ? Afl : Afh) + ((size_t)(kc * 8 + ocg) * 64 + l) * 8;
        gl2lds16(src, sp ? &L.st.al[buf][ocg][0][0] : &L.st.ah[buf][ocg][0][0]);
      } else {
        int j = q - 16;
        int sp = j >> 1, nc = j & 1;
        const ushort_t* src =
            (sp ? Bfl : Bfh) +
            (((size_t)kc * 102400 + (n0 + nc * 32 + (l & 31))) * 2 + (l >> 5)) * 8;
        gl2lds16(src, sp ? &L.st.bl[buf][nc][0][0] : &L.st.bh[buf][nc][0][0]);
      }
    }
  };

  stage(0, 0);
  __syncthreads();
  int buf = 0;
  for (int kc = 0; kc < 9; ++kc) {
    if (kc < 8) stage(buf ^ 1, kc + 1);
    short8 a0h = *(const short8*)&L.st.ah[buf][2 * w + 0][l][0];
    short8 a1h = *(const short8*)&L.st.ah[buf][2 * w + 1][l][0];
    short8 a0l = *(const short8*)&L.st.al[buf][2 * w + 0][l][0];
    short8 a1l = *(const short8*)&L.st.al[buf][2 * w + 1][l][0];
#pragma unroll
    for (int nc = 0; nc < 2; ++nc) {
      short8 bh = *(const short8*)&L.st.bh[buf][nc][l][0];
      short8 bl = *(const short8*)&L.st.bl[buf][nc][l][0];
      acc[0][nc] = __builtin_amdgcn_mfma_f32_32x32x16_bf16(a0h, bh, acc[0][nc], 0, 0, 0);
      acc[0][nc] = __builtin_amdgcn_mfma_f32_32x32x16_bf16(a0h, bl, acc[0][nc], 0, 0, 0);
      acc[0][nc] = __builtin_amdgcn_mfma_f32_32x32x16_bf16(a0l, bh, acc[0][nc], 0, 0, 0);
      acc[1][nc] = __builtin_amdgcn_mfma_f32_32x32x16_bf16(a1h, bh, acc[1][nc], 0, 0, 0);
      acc[1][nc] = __builtin_amdgcn_mfma_f32_32x32x16_bf16(a1h, bl, acc[1][nc], 0, 0, 0);
      acc[1][nc] = __builtin_amdgcn_mfma_f32_32x32x16_bf16(a1l, bh, acc[1][nc], 0, 0, 0);
    }
    __syncthreads();
    buf ^= 1;
  }

  // epilogue: bias+relu, LDS transpose, split-store xT[n][oc]
  for (int nc = 0; nc < 2; ++nc) {
    __syncthreads();
#pragma unroll
    for (int j = 0; j < 2; ++j)
#pragma unroll
      for (int r = 0; r < 16; ++r) {
        int row = w * 64 + j * 32 + (r & 3) + 8 * (r >> 2) + ((l >> 5) << 2);
        L.ep[row][l & 31] = fmaxf(acc[j][nc][r] + cb[row], 0.f);
      }
    __syncthreads();
    int nl = t >> 3, ocr = (t & 7) * 32;
    size_t ng = (size_t)(n0 + nc * 32 + nl);
#pragma unroll
    for (int q8 = 0; q8 < 4; ++q8) {
      short8 sh, sl;
#pragma unroll
      for (int e = 0; e < 8; ++e) {
        float vv = L.ep[ocr + q8 * 8 + e][nl];
        unsigned short h = f2bf(vv);
        sh[e] = (short)h;
        sl[e] = (short)f2bf(vv - bf2f(h));
      }
      *(short8*)&xTh[ng * 256 + ocr + q8 * 8] = sh;
      *(short8*)&xTl[ng * 256 + ocr + q8 * 8] = sl;
    }
  }
}

// === pw (256oc,256ic,9,9) fp32 -> A-fragment layout [kc][ocg][lane][8] =====
__global__ __launch_bounds__(256) void wcvt_kernel(const float* __restrict__ pw,
                                                   ushort_t* __restrict__ ah,
                                                   ushort_t* __restrict__ al) {
  int tid = blockIdx.x * 256 + threadIdx.x;  // 663552 = 1296*8*64
  int l = tid & 63;
  int ocg = (tid >> 6) & 7;
  int kc = tid >> 9;
  int oc = ocg * 32 + (l & 31);
  size_t obase = (size_t)tid * 8;
#pragma unroll
  for (int e = 0; e < 8; ++e) {
    int k = kc * 16 + ((l >> 5) << 3) + e;
    int kh = k / 2304;
    int r = k - kh * 2304;
    int kw = r >> 8, ic = r & 255;
    float v = pw[((size_t)oc * 256 + ic) * 81 + kh * 9 + kw];
    unsigned short h = f2bf(v);
    ah[obase + e] = h;
    al[obase + e] = f2bf(v - bf2f(h));
  }
}

// ================= primary conv as MFMA implicit GEMM ======================
__global__ __launch_bounds__(256, 2) void pgemm_kernel(
    const ushort_t* __restrict__ Agh, const ushort_t* __restrict__ Agl,
    const ushort_t* __restrict__ Xh, const ushort_t* __restrict__ Xl,
    float* __restrict__ part) {
  __shared__ __align__(16) ushort_t sA[2][2][2][4][64][8];
  __shared__ __align__(16) ushort_t sB[2][2][2][4][64][8];
  const int t = threadIdx.x;
  const int l = t & 63;
  const int w = t >> 6;
  const int wm = w >> 1, wn = w & 1;
  const int m0 = blockIdx.y;
  const int n0 = blockIdx.x * 128;
  const int zk = blockIdx.z;
  const int kcb = zk * 162;

  int n = n0 + w * 32 + (l & 31);
  int b_ = n / 36;
  int pos = n - b_ * 36;
  int ph = pos / 6, pww = pos - ph * 6;
  size_t pbase = (((size_t)b_ * 20 + 2 * ph) * 20 + 2 * pww) * 256 + ((l >> 5) << 3);

  const int sw = w >> 1, klw = w & 1;
  const ushort_t* Asrc = sw ? Agl : Agh;
  const size_t aoff0 = (((size_t)(kcb + klw) * 8 + m0 * 4) * 64 + l) * 8;

  f32x16 acc[2][2];
#pragma unroll
  for (int j = 0; j < 2; ++j)
#pragma unroll
    for (int j2 = 0; j2 < 2; ++j2)
#pragma unroll
      for (int r = 0; r < 16; ++r) acc[j][j2][r] = 0.f;

  auto koff = [](int kc) {
    int kh = (unsigned)kc / 144u;
    int r = kc - kh * 144;
    return ((kh * 20 + (r >> 4)) << 8) + ((r & 15) << 4);
  };
  auto stage = [&](int buf, int step) {
    size_t ao = aoff0 + (size_t)step * 8192;
#pragma unroll
    for (int j = 0; j < 4; ++j)
      gl2lds16(Asrc + ao + j * 512, &sA[buf][sw][klw][j][0][0]);
    int kc0 = kcb + 2 * step;
    int o0 = koff(kc0), o1 = koff(kc0 + 1);
    gl2lds16(Xh + pbase + o0, &sB[buf][0][0][w][0][0]);
    gl2lds16(Xh + pbase + o1, &sB[buf][0][1][w][0][0]);
    gl2lds16(Xl + pbase + o0, &sB[buf][1][0][w][0][0]);
    gl2lds16(Xl + pbase + o1, &sB[buf][1][1][w][0][0]);
  };

  stage(0, 0);
  __syncthreads();
  int buf = 0;
  for (int step = 0; step < 81; ++step) {
    if (step + 1 < 81) stage(buf ^ 1, step + 1);
#pragma unroll
    for (int kl = 0; kl < 2; ++kl) {
      short8 a0h = *(const short8*)&sA[buf][0][kl][wm * 2 + 0][l][0];
      short8 a1h = *(const short8*)&sA[buf][0][kl][wm * 2 + 1][l][0];
      short8 a0l = *(const short8*)&sA[buf][1][kl][wm * 2 + 0][l][0];
      short8 a1l = *(const short8*)&sA[buf][1][kl][wm * 2 + 1][l][0];
      short8 b0h = *(const short8*)&sB[buf][0][kl][wn * 2 + 0][l][0];
      short8 b1h = *(const short8*)&sB[buf][0][kl][wn * 2 + 1][l][0];
      short8 b0l = *(const short8*)&sB[buf][1][kl][wn * 2 + 0][l][0];
      short8 b1l = *(const short8*)&sB[buf][1][kl][wn * 2 + 1][l][0];
      acc[0][0] = __builtin_amdgcn_mfma_f32_32x32x16_bf16(a0h, b0h, acc[0][0], 0, 0, 0);
      acc[0][0] = __builtin_amdgcn_mfma_f32_32x32x16_bf16(a0h, b0l, acc[0][0], 0, 0, 0);
      acc[0][0] = __builtin_amdgcn_mfma_f32_32x32x16_bf16(a0l, b0h, acc[0][0], 0, 0, 0);
      acc[0][1] = __builtin_amdgcn_mfma_f32_32x32x16_bf16(a0h, b1h, acc[0][1], 0, 0, 0);
      acc[0][1] = __builtin_amdgcn_mfma_f32_32x32x16_bf16(a0h, b1l, acc[0][1], 0, 0, 0);
      acc[0][1] = __builtin_amdgcn_mfma_f32_32x32x16_bf16(a0l, b1h, acc[0][1], 0, 0, 0);
      acc[1][0] = __builtin_amdgcn_mfma_f32_32x32x16_bf16(a1h, b0h, acc[1][0], 0, 0, 0);
      acc[1][0] = __builtin_amdgcn_mfma_f32_32x32x16_bf16(a1h, b0l, acc[1][0], 0, 0, 0);
      acc[1][0] = __builtin_amdgcn_mfma_f32_32x32x16_bf16(a1l, b0h, acc[1][0], 0, 0, 0);
      acc[1][1] = __builtin_amdgcn_mfma_f32_32x32x16_bf16(a1h, b1h, acc[1][1], 0, 0, 0);
      acc[1][1] = __builtin_amdgcn_mfma_f32_32x32x16_bf16(a1h, b1l, acc[1][1], 0, 0, 0);
      acc[1][1] = __builtin_amdgcn_mfma_f32_32x32x16_bf16(a1l, b1h, acc[1][1], 0, 0, 0);
    }
    __syncthreads();
    buf ^= 1;
  }

#pragma unroll
  for (int j = 0; j < 2; ++j)
#pragma unroll
    for (int j2 = 0; j2 < 2; ++j2) {
      int ocb = m0 * 128 + wm * 64 + j * 32;
      int nb = n0 + wn * 64 + j2 * 32 + (l & 31);
#pragma unroll
      for (int r = 0; r < 16; ++r) {
        int row = (r & 3) + 8 * (r >> 2) + ((l >> 5) << 2);
        part[((size_t)(zk * 256 + ocb + row)) * 9216 + nb] = acc[j][j2][r];
      }
    }
}

// === u[b][oc*36+pos] = bias[oc] + sum_z part[z][oc][n], n = b*36+pos ========
__global__ __launch_bounds__(256) void ured_kernel(const float* __restrict__ part,
                                                   const float* __restrict__ pb,
                                                   float* __restrict__ u) {
  int tid = blockIdx.x * 256 + threadIdx.x;
  int oc = tid / 9216;
  int n = tid - oc * 9216;
  float s = pb[oc];
#pragma unroll
  for (int z = 0; z < 8; ++z) s += part[((size_t)z * 256 + oc) * 9216 + n];
  int b = n / 36;
  int pos = n - b * 36;
  u[(size_t)b * 9216 + oc * 36 + pos] = s;
}

// ======= squash + convert: u fp32 -> ub (b-major) & ut (k-major) hi/lo =====
__global__ __launch_bounds__(256) void sqcvt_kernel(const float* __restrict__ u,
                                                    ushort_t* __restrict__ ubh,
                                                    ushort_t* __restrict__ ubl,
                                                    ushort_t* __restrict__ uth,
                                                    ushort_t* __restrict__ utl) {
  int kt = blockIdx.x, bt = blockIdx.y;
  int k0 = kt * 64, b0 = bt * 64;
  __shared__ ushort_t lh[64][66], ll_[64][66];
  int t = threadIdx.x;
#pragma unroll
  for (int jj = 0; jj < 2; ++jj) {
    int item = t + 256 * jj;
    int g = item & 7, bl = item >> 3;
    int b = b0 + bl, kb = k0 + g * 8;
    const float4* p4 = reinterpret_cast<const float4*>(u + (size_t)b * 9216 + kb);
    float4 v0 = p4[0], v1 = p4[1];
    float va[8] = {v0.x, v0.y, v0.z, v0.w, v1.x, v1.y, v1.z, v1.w};
    float sn = 0.f;
#pragma unroll
    for (int e = 0; e < 8; ++e) sn += va[e] * va[e];
    float f = sn / ((1.f + sn) * sqrtf(sn));
    short8 sh, sl;
#pragma unroll
    for (int e = 0; e < 8; ++e) {
      float vv = va[e] * f;
      unsigned short h = f2bf(vv);
      unsigned short lo = f2bf(vv - bf2f(h));
      sh[e] = (short)h;
      sl[e] = (short)lo;
      lh[g * 8 + e][bl] = h;
      ll_[g * 8 + e][bl] = lo;
    }
    *(short8*)&ubh[(size_t)b * 9216 + kb] = sh;
    *(short8*)&ubl[(size_t)b * 9216 + kb] = sl;
  }
  __syncthreads();
  int kl = t >> 2, br = (t & 3) * 16;
#pragma unroll
  for (int q = 0; q < 2; ++q) {
    short8 sh, sl;
#pragma unroll
    for (int e = 0; e < 8; ++e) {
      sh[e] = (short)lh[kl][br + q * 8 + e];
      sl[e] = (short)ll_[kl][br + q * 8 + e];
    }
    *(short8*)&uth[(size_t)(k0 + kl) * 256 + b0 + br + q * 8] = sh;
    *(short8*)&utl[(size_t)(k0 + kl) * 256 + b0 + br + q * 8] = sl;
  }
}

// ================================ helpers ==================================
__global__ void zero_kernel(float* __restrict__ p, int n) {
  int i = blockIdx.x * 256 + threadIdx.x;
  if (i < n) p[i] = 0.f;
}

__global__ __launch_bounds__(256) void softmax_c_kernel(const float* __restrict__ bp,
                                                        float* __restrict__ c) {
  int cls = blockIdx.x;
  int t = threadIdx.x;
  __shared__ float red[256];
  float m = -1e30f;
  for (int r = t; r < 1152; r += 256) m = fmaxf(m, bp[r * 10 + cls]);
  red[t] = m;
  __syncthreads();
  for (int s = 128; s > 0; s >>= 1) {
    if (t < s) red[t] = fmaxf(red[t], red[t + s]);
    __syncthreads();
  }
  m = red[0];
  __syncthreads();
  float sum = 0.f;
  for (int r = t; r < 1152; r += 256) sum += expf(bp[r * 10 + cls] - m);
  red[t] = sum;
  __syncthreads();
  for (int s = 128; s > 0; s >>= 1) {
    if (t < s) red[t] += red[t + s];
    __syncthreads();
  }
  float den = red[0];
  for (int r = t; r < 1152; r += 256) c[r * 10 + cls] = expf(bp[r * 10 + cls] - m) / den;
}

// WCb[col 160][k 9216] bf16 hi/lo, col=cls*16+o, k=r*8+i; val = W*c
__global__ __launch_bounds__(256) void wcb_kernel(const float* __restrict__ W,
                                                  const float* __restrict__ c,
                                                  ushort_t* __restrict__ wh,
                                                  ushort_t* __restrict__ wl) {
  int tid = blockIdx.x * 256 + threadIdx.x;  // 184320 = 160*1152
  int col = tid / 1152;
  int kg = tid - col * 1152;  // = r
  int cls = col >> 4, o = col & 15;
  float cc = c[kg * 10 + cls];
  const float4* wp = reinterpret_cast<const float4*>(W + (((size_t)kg * 10 + cls) * 16 + o) * 8);
  float4 w0 = wp[0], w1 = wp[1];
  float wa[8] = {w0.x, w0.y, w0.z, w0.w, w1.x, w1.y, w1.z, w1.w};
  short8 sh, sl;
#pragma unroll
  for (int e = 0; e < 8; ++e) {
    float vv = wa[e] * cc;
    unsigned short h = f2bf(vv);
    sh[e] = (short)h;
    sl[e] = (short)f2bf(vv - bf2f(h));
  }
  *(short8*)&wh[(size_t)col * 9216 + kg * 8] = sh;
  *(short8*)&wl[(size_t)col * 9216 + kg * 8] = sl;
}

// ======================= s-GEMM via MFMA (1 wave/block) ====================
// s_part[ks 144][b 256][col 160]; block: 64 b x 160 col x 64 k
__global__ __launch_bounds__(64, 1) void smfma_kernel(
    const ushort_t* __restrict__ ubh, const ushort_t* __restrict__ ubl,
    const ushort_t* __restrict__ wh, const ushort_t* __restrict__ wl,
    float* __restrict__ s_part) {
  int ks = blockIdx.x, bt = blockIdx.y;
  __shared__ __align__(16) ushort_t Ah[4][2][64][8], Al[4][2][64][8];
  __shared__ __align__(16) ushort_t Bh[4][5][64][8], Bl[4][5][64][8];
  int l = threadIdx.x;
  int k0 = ks * 64;
#pragma unroll
  for (int kc = 0; kc < 4; ++kc) {
#pragma unroll
    for (int mh = 0; mh < 2; ++mh) {
      size_t ao = (size_t)(bt * 64 + mh * 32 + (l & 31)) * 9216 + k0 + kc * 16 + ((l >> 5) << 3);
      gl2lds16(ubh + ao, &Ah[kc][mh][0][0]);
      gl2lds16(ubl + ao, &Al[kc][mh][0][0]);
    }
#pragma unroll
    for (int cf = 0; cf < 5; ++cf) {
      size_t bo = (size_t)(cf * 32 + (l & 31)) * 9216 + k0 + kc * 16 + ((l >> 5) << 3);
      gl2lds16(wh + bo, &Bh[kc][cf][0][0]);
      gl2lds16(wl + bo, &Bl[kc][cf][0][0]);
    }
  }
  __builtin_amdgcn_s_waitcnt(0);
  __syncthreads();
  f32x16 acc[2][5];
#pragma unroll
  for (int m = 0; m < 2; ++m)
#pragma unroll
    for (int cf = 0; cf < 5; ++cf)
#pragma unroll
      for (int r = 0; r < 16; ++r) acc[m][cf][r] = 0.f;
#pragma unroll
  for (int kc = 0; kc < 4; ++kc) {
    short8 a0h = *(const short8*)&Ah[kc][0][l][0];
    short8 a1h = *(const short8*)&Ah[kc][1][l][0];
    short8 a0l = *(const short8*)&Al[kc][0][l][0];
    short8 a1l = *(const short8*)&Al[kc][1][l][0];
#pragma unroll
    for (int cf = 0; cf < 5; ++cf) {
      short8 bh = *(const short8*)&Bh[kc][cf][l][0];
      short8 bl = *(const short8*)&Bl[kc][cf][l][0];
      acc[0][cf] = __builtin_amdgcn_mfma_f32_32x32x16_bf16(a0h, bh, acc[0][cf], 0, 0, 0);
      acc[0][cf] = __builtin_amdgcn_mfma_f32_32x32x16_bf16(a0h, bl, acc[0][cf], 0, 0, 0);
      acc[0][cf] = __builtin_amdgcn_mfma_f32_32x32x16_bf16(a0l, bh, acc[0][cf], 0, 0, 0);
      acc[1][cf] = __builtin_amdgcn_mfma_f32_32x32x16_bf16(a1h, bh, acc[1][cf], 0, 0, 0);
      acc[1][cf] = __builtin_amdgcn_mfma_f32_32x32x16_bf16(a1h, bl, acc[1][cf], 0, 0, 0);
      acc[1][cf] = __builtin_amdgcn_mfma_f32_32x32x16_bf16(a1l, bh, acc[1][cf], 0, 0, 0);
    }
  }
#pragma unroll
  for (int mh = 0; mh < 2; ++mh)
#pragma unroll
    for (int cf = 0; cf < 5; ++cf)
#pragma unroll
      for (int r = 0; r < 16; ++r) {
        int row = bt * 64 + mh * 32 + (r & 3) + 8 * (r >> 2) + ((l >> 5) << 2);
        s_part[((size_t)ks * 256 + row) * 160 + cf * 32 + (l & 31)] = acc[mh][cf][r];
      }
}

// v = f(sum of 144 partials); also vT bf16 hi/lo; optional out
__global__ __launch_bounds__(256) void reduce_v_kernel(
    const float* __restrict__ s_part, float* __restrict__ v,
    ushort_t* __restrict__ vth, ushort_t* __restrict__ vtl,
    float* __restrict__ out, int write_out) {
  int i = blockIdx.x * 256 + threadIdx.x;  // 40960
  float s0 = 0.f, s1 = 0.f, s2 = 0.f, s3 = 0.f;
#pragma unroll 4
  for (int ks = 0; ks < 144; ks += 4) {
    s0 += s_part[(size_t)ks * 40960 + i];
    s1 += s_part[(size_t)(ks + 1) * 40960 + i];
    s2 += s_part[(size_t)(ks + 2) * 40960 + i];
    s3 += s_part[(size_t)(ks + 3) * 40960 + i];
  }
  float s = (s0 + s1) + (s2 + s3);
  float val = s * fabsf(s) / (1.f + s * s);
  v[i] = val;
  int b = i / 160, col = i - b * 160;
  unsigned short h = f2bf(val);
  vth[col * 256 + b] = h;
  vtl[col * 256 + b] = f2bf(val - bf2f(h));
  if (write_out) out[i] = val;
}

// ====================== T-GEMM via MFMA: T[k][col] =========================
struct StageT {
  ushort_t ah[2][2][2][64][8];
  ushort_t al[2][2][2][64][8];
  ushort_t bh[2][2][5][64][8];
  ushort_t bl[2][2][5][64][8];
};
__global__ __launch_bounds__(256) void tmfma_kernel(
    const ushort_t* __restrict__ uth, const ushort_t* __restrict__ utl,
    const ushort_t* __restrict__ vth, const ushort_t* __restrict__ vtl,
    float* __restrict__ Tp) {
  __shared__ __align__(16) union { StageT st; float red[2][32][160]; } L;
  int mt = blockIdx.x, kh = blockIdx.y;
  int t = threadIdx.x;
  int l = t & 63, w = t >> 6;
  int wm = w & 1, wk = w >> 1;
  int m0 = mt * 64;

  auto stage = [&](int buf, int step) {
    int kb = kh * 128 + wk * 64 + step * 16;
    size_t ao = (size_t)(m0 + wm * 32 + (l & 31)) * 256 + kb + ((l >> 5) << 3);
    gl2lds16(uth + ao, &L.st.ah[buf][wk][wm][0][0]);
    gl2lds16(utl + ao, &L.st.al[buf][wk][wm][0][0]);
#pragma unroll
    for (int q = 0; q < 5; ++q) {
      int qq = wm * 5 + q;
      int cf = qq >> 1, sp = qq & 1;
      size_t bo = (size_t)(cf * 32 + (l & 31)) * 256 + kb + ((l >> 5) << 3);
      gl2lds16((sp ? vtl : vth) + bo,
               sp ? &L.st.bl[buf][wk][cf][0][0] : &L.st.bh[buf][wk][cf][0][0]);
    }
  };

  f32x16 acc[5];
#pragma unroll
  for (int cf = 0; cf < 5; ++cf)
#pragma unroll
    for (int r = 0; r < 16; ++r) acc[cf][r] = 0.f;

  stage(0, 0);
  __syncthreads();
  int buf = 0;
  for (int step = 0; step < 4; ++step) {
    if (step < 3) stage(buf ^ 1, step + 1);
    short8 ah = *(const short8*)&L.st.ah[buf][wk][wm][l][0];
    short8 al = *(const short8*)&L.st.al[buf][wk][wm][l][0];
#pragma unroll
    for (int cf = 0; cf < 5; ++cf) {
      short8 bh = *(const short8*)&L.st.bh[buf][wk][cf][l][0];
      short8 bl = *(const short8*)&L.st.bl[buf][wk][cf][l][0];
      acc[cf] = __builtin_amdgcn_mfma_f32_32x32x16_bf16(ah, bh, acc[cf], 0, 0, 0);
      acc[cf] = __builtin_amdgcn_mfma_f32_32x32x16_bf16(ah, bl, acc[cf], 0, 0, 0);
      acc[cf] = __builtin_amdgcn_mfma_f32_32x32x16_bf16(al, bh, acc[cf], 0, 0, 0);
    }
    __syncthreads();
    buf ^= 1;
  }
  // cross-wk reduce via LDS
  if (wk == 1) {
#pragma unroll
    for (int cf = 0; cf < 5; ++cf)
#pragma unroll
      for (int r = 0; r < 16; ++r) {
        int row = (r & 3) + 8 * (r >> 2) + ((l >> 5) << 2);
        L.red[wm][row][cf * 32 + (l & 31)] = acc[cf][r];
      }
  }
  __syncthreads();
  if (wk == 0) {
    const float scl = 1.f / 256.f;
#pragma unroll
    for (int cf = 0; cf < 5; ++cf)
#pragma unroll
      for (int r = 0; r < 16; ++r) {
        int row = (r & 3) + 8 * (r >> 2) + ((l >> 5) << 2);
        int col = cf * 32 + (l & 31);
        float val = (acc[cf][r] + L.red[wm][row][col]) * scl;
        Tp[((size_t)kh * 9216 + m0 + wm * 32 + row) * 160 + col] = val;
      }
  }
}

// bp[r,cls] += sum_{o,i} W[r,cls,o,i] * (T0+T1)[(r,i),(cls,o)]
__global__ __launch_bounds__(256) void bp_update_kernel(const float* __restrict__ W,
                                                        const float* __restrict__ Tp,
                                                        float* __restrict__ bp) {
  int idx = blockIdx.x * 256 + threadIdx.x;
  if (idx >= 11520) return;
  int r = idx / 10, cls = idx % 10;
  const float* wp = W + (size_t)idx * 128;
  const float* T1 = Tp + 1474560;
  float s = 0.f;
#pragma unroll
  for (int o = 0; o < 16; ++o)
#pragma unroll
    for (int i = 0; i < 8; ++i) {
      size_t ti = (size_t)(r * 8 + i) * 160 + cls * 16 + o;
      s = fmaf(wp[o * 8 + i], Tp[ti] + T1[ti], s);
    }
  bp[idx] += s;
}

// class norms -> softmax over batch -> argmax -> masked + (bi, tsel)
__global__ __launch_bounds__(256) void mask_kernel(const float* __restrict__ v,
                                                   float* __restrict__ masked,
                                                   int* __restrict__ bi_out,
                                                   float* __restrict__ tsel) {
  __shared__ float cls_s[256][10];
  __shared__ float colmax[10], colden[10];
  int t = threadIdx.x;
  float cl[10];
  for (int c = 0; c < 10; ++c) {
    float sum = 0.f;
    for (int o = 0; o < 16; ++o) {
      float q = v[t * 160 + c * 16 + o];
      sum += q * q;
    }
    cl[c] = sqrtf(sum);
    cls_s[t][c] = cl[c];
  }
  __syncthreads();
  if (t < 10) {
    float m = -1e30f;
    for (int b = 0; b < 256; ++b) m = fmaxf(m, cls_s[b][t]);
    float d = 0.f;
    for (int b = 0; b < 256; ++b) d += expf(cls_s[b][t] - m);
    colmax[t] = m;
    colden[t] = d;
  }
  __syncthreads();
  float best = -1e30f;
  int bi = 0;
  for (int c = 0; c < 10; ++c) {
    float p = expf(cl[c] - colmax[c]) / colden[c];
    if (p > best) { best = p; bi = c; }
  }
  for (int c = 0; c < 10; ++c) masked[t * 10 + c] = (c == bi) ? 1.f : 0.f;
  bi_out[t] = bi;
  for (int o = 0; o < 16; ++o) tsel[t * 16 + o] = v[t * 160 + bi * 16 + o];
}

// fc1 exploiting mask sparsity: K=16
__global__ __launch_bounds__(256) void fc1s_kernel(const float* __restrict__ tsel,
                                                   const int* __restrict__ bi,
                                                   const float* __restrict__ w1,
                                                   const float* __restrict__ b1,
                                                   float* __restrict__ h1) {
  int b = blockIdx.x;
  int t = threadIdx.x;
  __shared__ float ts[16];
  __shared__ int sbi;
  if (t < 16) ts[t] = tsel[b * 16 + t];
  if (t == 0) sbi = bi[b];
  __syncthreads();
  for (int j = t; j < 512; j += 256) {
    const float* wp = w1 + (size_t)j * 160 + sbi * 16;
    float a = b1[j];
#pragma unroll
    for (int o = 0; o < 16; ++o) a = fmaf(ts[o], wp[o], a);
    h1[(size_t)b * 512 + j] = fmaxf(a, 0.f);
  }
}

template <int ACT>
__global__ __launch_bounds__(256) void fc_kernel(const float* __restrict__ in,
                                                 const float* __restrict__ w,
                                                 const float* __restrict__ bias,
                                                 float* __restrict__ out, int K, int N) {
  int jt = blockIdx.x, bt = blockIdx.y;
  __shared__ float in_s[16][33];
  __shared__ float w_s[64][33];
  int t = threadIdx.x;
  int jl = t & 63, bq = t >> 6;
  float acc[4] = {0, 0, 0, 0};
  for (int k0 = 0; k0 < K; k0 += 32) {
    __syncthreads();
    for (int q = t; q < 512; q += 256) {
      int bb = q >> 5, kk = q & 31;
      in_s[bb][kk] = in[(size_t)(bt * 16 + bb) * K + k0 + kk];
    }
    for (int q = t; q < 2048; q += 256) {
      int jj = q >> 5, kk = q & 31;
      int jg = jt * 64 + jj;
      w_s[jj][kk] = (jg < N) ? w[(size_t)jg * K + k0 + kk] : 0.f;
    }
    __syncthreads();
#pragma unroll
    for (int kk = 0; kk < 32; ++kk) {
      float wv = w_s[jl][kk];
#pragma unroll
      for (int m = 0; m < 4; ++m) acc[m] = fmaf(in_s[bq * 4 + m][kk], wv, acc[m]);
    }
  }
  int jg = jt * 64 + jl;
  if (jg < N) {
    float bv = bias[jg];
    for (int m = 0; m < 4; ++m) {
      float r = acc[m] + bv;
      if (ACT == 0)
        r = fmaxf(r, 0.f);
      else
        r = 1.f / (1.f + expf(-r));
      out[(size_t)(bt * 16 + bq * 4 + m) * N + jg] = r;
    }
  }
}

// ===========================================================================
extern "C" void kernel_launch(void* const* d_in, const int* in_sizes, int n_in,
                              void* d_out, int out_size, void* d_ws, size_t ws_size,
                              hipStream_t stream) {
  const float* data  = (const float*)d_in[0];
  const float* convw = (const float*)d_in[1];
  const float* convb = (const float*)d_in[2];
  const float* pcw   = (const float*)d_in[3];
  const float* pcb   = (const float*)d_in[4];
  const float* W     = (const float*)d_in[5];
  const float* w1    = (const float*)d_in[6];
  const float* b1    = (const float*)d_in[7];
  const float* w2    = (const float*)d_in[8];
  const float* b2    = (const float*)d_in[9];
  const float* w3    = (const float*)d_in[10];
  const float* b3    = (const float*)d_in[11];
  float* out = (float*)d_out;

  char* wsb = (char*)d_ws;
  size_t off = 0;
  auto allocb = [&](size_t bytes) {
    void* p = wsb + off;
    off += (bytes + 255) & ~(size_t)255;
    return p;
  };
  // region 0: Bfrag (phase1) -> pgemm partials (phase2) -> ub/ut bf16 (phase3)
  float* part = (float*)allocb(75497472);  // 8*256*9216*4
  ushort_t* Bfh = (ushort_t*)part;
  ushort_t* Bfl = Bfh + 14745600;          // 9*102400*16
  ushort_t* ubh = (ushort_t*)part;
  ushort_t* ubl = ubh + 2359296;
  ushort_t* uth = ubl + 2359296;
  ushort_t* utl = uth + 2359296;
  float* u    = (float*)allocb(9437184);   // (256,9216) fp32
  float* v    = (float*)allocb(163840);
  float* bp   = (float*)allocb(46080);
  float* c    = (float*)allocb(46080);
  ushort_t* WCbh = (ushort_t*)allocb(2949120);
  ushort_t* WCbl = (ushort_t*)allocb(2949120);
  ushort_t* vth  = (ushort_t*)allocb(81920);
  ushort_t* vtl  = (ushort_t*)allocb(81920);
  int*   bi   = (int*)allocb(1024);
  float* tsel = (float*)allocb(16384);
  // region: s_part (iter) / T_part (iter) / h1,h2 (tail) — disjoint lifetimes
  float* s_part = (float*)allocb(23592960);  // 144*256*160*4
  float* Tp = s_part;                        // 2*9216*160*4 = 11.8MB
  float* h1 = s_part;                        // 256*512*4
  float* h2 = s_part + 131072;               // 256*1024*4
  ushort_t* Agh = (ushort_t*)allocb(10616832);
  ushort_t* Agl = (ushort_t*)allocb(10616832);
  ushort_t* Afch = (ushort_t*)allocb(147456);
  ushort_t* Afcl = (ushort_t*)allocb(147456);
  ushort_t* xTh = (ushort_t*)allocb(52428800);  // [n=102400][256] bf16 hi
  ushort_t* xTl = (ushort_t*)allocb(52428800);
  if (ws_size < off) return;

  acvt_kernel<<<18, 256, 0, stream>>>(convw, Afch, Afcl);
  im2col_kernel<<<7200, 256, 0, stream>>>(data, Bfh, Bfl);
  cgemm_kernel<<<1600, 256, 0, stream>>>(Afch, Afcl, Bfh, Bfl, convb, xTh, xTl);
  wcvt_kernel<<<2592, 256, 0, stream>>>(pcw, Agh, Agl);
  pgemm_kernel<<<dim3(72, 2, 8), 256, 0, stream>>>(Agh, Agl, xTh, xTl, part);
  ured_kernel<<<9216, 256, 0, stream>>>(part, pcb, u);
  sqcvt_kernel<<<dim3(144, 4), 256, 0, stream>>>(u, ubh, ubl, uth, utl);
  zero_kernel<<<45, 256, 0, stream>>>(bp, 11520);

  for (int it = 0; it < 3; ++it) {
    softmax_c_kernel<<<10, 256, 0, stream>>>(bp, c);
    wcb_kernel<<<720, 256, 0, stream>>>(W, c, WCbh, WCbl);
    smfma_kernel<<<dim3(144, 4), 64, 0, stream>>>(ubh, ubl, WCbh, WCbl, s_part);
    reduce_v_kernel<<<160, 256, 0, stream>>>(s_part, v, vth, vtl, out, it == 2 ? 1 : 0);
    if (it < 2) {
      tmfma_kernel<<<dim3(144, 2), 256, 0, stream>>>(uth, utl, vth, vtl, Tp);
      bp_update_kernel<<<45, 256, 0, stream>>>(W, Tp, bp);
    }
  }

  mask_kernel<<<1, 256, 0, stream>>>(v, out + 241664, bi, tsel);
  fc1s_kernel<<<256, 256, 0, stream>>>(tsel, bi, w1, b1, h1);
  fc_kernel<0><<<dim3(16, 16), 256, 0, stream>>>(h1, w2, b2, h2, 512, 1024);
  fc_kernel<1><<<dim3(13, 16), 256, 0, stream>>>(h2, w3, b3, out + 40960, 1024, 784);
}

// Round 4
// 904.590 us; speedup vs baseline: 5.0829x; 1.1028x over previous
//
#include <hip/hip_runtime.h>
#include <math.h>

typedef __attribute__((ext_vector_type(8))) short short8;
typedef __attribute__((ext_vector_type(16))) float f32x16;
typedef unsigned short ushort_t;

static __device__ __forceinline__ unsigned short f2bf(float f) {
  unsigned int u = __float_as_uint(f);
  u += 0x7FFF + ((u >> 16) & 1);  // RNE
  return (unsigned short)(u >> 16);
}
static __device__ __forceinline__ float bf2f(unsigned short h) {
  return __uint_as_float(((unsigned int)h) << 16);
}

__device__ __forceinline__ void gl2lds16(const void* g, void* l) {
  __builtin_amdgcn_global_load_lds(
      (const __attribute__((address_space(1))) unsigned int*)g,
      (__attribute__((address_space(3))) unsigned int*)l, 16, 0, 0);
}

// ======= conv1 A: conv_w (256,81) -> frag layout [kc 9][ocg 8][64][8] ======
// k = kh*16 + kwp (kwp 0..15, zero-pad kwp>=9)
__global__ __launch_bounds__(256) void acvt_kernel(const float* __restrict__ cw,
                                                   ushort_t* __restrict__ ah,
                                                   ushort_t* __restrict__ al) {
  int tid = blockIdx.x * 256 + threadIdx.x;  // 4608 = 9*8*64
  if (tid >= 4608) return;
  int l = tid & 63;
  int ocg = (tid >> 6) & 7;
  int kc = tid >> 9;  // = kh
  int oc = ocg * 32 + (l & 31);
  size_t obase = (size_t)tid * 8;
#pragma unroll
  for (int e = 0; e < 8; ++e) {
    int kwp = ((l >> 5) << 3) + e;
    float v = (kwp < 9) ? cw[oc * 81 + kc * 9 + kwp] : 0.f;
    unsigned short h = f2bf(v);
    ah[obase + e] = h;
    al[obase + e] = f2bf(v - bf2f(h));
  }
}

// ====== conv1 as MFMA GEMM, im2col fused (per-lane reg fragments) ==========
// C[256 oc][n=102400] -> bias+relu -> xT[n][oc] bf16 hi/lo
__global__ __launch_bounds__(256, 2) void cgemm_kernel(
    const ushort_t* __restrict__ Afh, const ushort_t* __restrict__ Afl,
    const float* __restrict__ data, const float* __restrict__ cb,
    ushort_t* __restrict__ xTh, ushort_t* __restrict__ xTl) {
  __shared__ float ep[256][33];
  const int t = threadIdx.x;
  const int l = t & 63;
  const int w = t >> 6;  // wave = oc-group of 64 (2 ocg of 32)
  const int n0 = blockIdx.x * 64;
  const int half = l >> 5;

  const float* rowp0;
  const float* rowp1;
  {
    int n = n0 + (l & 31);
    int b = n / 400, pos = n - b * 400;
    int ph = pos / 20, pw = pos - ph * 20;
    rowp0 = data + b * 784 + ph * 28 + pw;
    n = n0 + 32 + (l & 31);
    b = n / 400; pos = n - b * 400;
    ph = pos / 20; pw = pos - ph * 20;
    rowp1 = data + b * 784 + ph * 28 + pw;
  }

  f32x16 acc[2][2];
#pragma unroll
  for (int j = 0; j < 2; ++j)
#pragma unroll
    for (int nc = 0; nc < 2; ++nc)
#pragma unroll
      for (int r = 0; r < 16; ++r) acc[j][nc][r] = 0.f;

  for (int kc = 0; kc < 9; ++kc) {
    short8 a0h = *(const short8*)&Afh[((size_t)(kc * 8 + 2 * w + 0) * 64 + l) * 8];
    short8 a1h = *(const short8*)&Afh[((size_t)(kc * 8 + 2 * w + 1) * 64 + l) * 8];
    short8 a0l = *(const short8*)&Afl[((size_t)(kc * 8 + 2 * w + 0) * 64 + l) * 8];
    short8 a1l = *(const short8*)&Afl[((size_t)(kc * 8 + 2 * w + 1) * 64 + l) * 8];
#pragma unroll
    for (int nc = 0; nc < 2; ++nc) {
      const float* rp = (nc ? rowp1 : rowp0) + kc * 28;
      short8 bh8, bl8;
#pragma unroll
      for (int e = 0; e < 8; ++e) {
        int kwp = half * 8 + e;
        float v = (kwp < 9) ? rp[kwp] : 0.f;
        unsigned short h = f2bf(v);
        bh8[e] = (short)h;
        bl8[e] = (short)f2bf(v - bf2f(h));
      }
      acc[0][nc] = __builtin_amdgcn_mfma_f32_32x32x16_bf16(a0h, bh8, acc[0][nc], 0, 0, 0);
      acc[0][nc] = __builtin_amdgcn_mfma_f32_32x32x16_bf16(a0h, bl8, acc[0][nc], 0, 0, 0);
      acc[0][nc] = __builtin_amdgcn_mfma_f32_32x32x16_bf16(a0l, bh8, acc[0][nc], 0, 0, 0);
      acc[1][nc] = __builtin_amdgcn_mfma_f32_32x32x16_bf16(a1h, bh8, acc[1][nc], 0, 0, 0);
      acc[1][nc] = __builtin_amdgcn_mfma_f32_32x32x16_bf16(a1h, bl8, acc[1][nc], 0, 0, 0);
      acc[1][nc] = __builtin_amdgcn_mfma_f32_32x32x16_bf16(a1l, bh8, acc[1][nc], 0, 0, 0);
    }
  }

  // epilogue: bias+relu, LDS transpose, split-store xT[n][oc]
  for (int nc = 0; nc < 2; ++nc) {
    __syncthreads();
#pragma unroll
    for (int j = 0; j < 2; ++j)
#pragma unroll
      for (int r = 0; r < 16; ++r) {
        int row = w * 64 + j * 32 + (r & 3) + 8 * (r >> 2) + ((l >> 5) << 2);
        ep[row][l & 31] = fmaxf(acc[j][nc][r] + cb[row], 0.f);
      }
    __syncthreads();
    int nl = t >> 3, ocr = (t & 7) * 32;
    size_t ng = (size_t)(n0 + nc * 32 + nl);
#pragma unroll
    for (int q8 = 0; q8 < 4; ++q8) {
      short8 sh, sl;
#pragma unroll
      for (int e = 0; e < 8; ++e) {
        float vv = ep[ocr + q8 * 8 + e][nl];
        unsigned short h = f2bf(vv);
        sh[e] = (short)h;
        sl[e] = (short)f2bf(vv - bf2f(h));
      }
      *(short8*)&xTh[ng * 256 + ocr + q8 * 8] = sh;
      *(short8*)&xTl[ng * 256 + ocr + q8 * 8] = sl;
    }
  }
}

// === pw (256oc,256ic,9,9) fp32 -> A-fragment layout [kc][ocg][lane][8] =====
__global__ __launch_bounds__(256) void wcvt_kernel(const float* __restrict__ pw,
                                                   ushort_t* __restrict__ ah,
                                                   ushort_t* __restrict__ al) {
  int tid = blockIdx.x * 256 + threadIdx.x;  // 663552 = 1296*8*64
  int l = tid & 63;
  int ocg = (tid >> 6) & 7;
  int kc = tid >> 9;
  int oc = ocg * 32 + (l & 31);
  size_t obase = (size_t)tid * 8;
#pragma unroll
  for (int e = 0; e < 8; ++e) {
    int k = kc * 16 + ((l >> 5) << 3) + e;
    int kh = k / 2304;
    int r = k - kh * 2304;
    int kw = r >> 8, ic = r & 255;
    float v = pw[((size_t)oc * 256 + ic) * 81 + kh * 9 + kw];
    unsigned short h = f2bf(v);
    ah[obase + e] = h;
    al[obase + e] = f2bf(v - bf2f(h));
  }
}

// ====== primary conv as MFMA implicit GEMM, depth-2 counted-vmcnt pipe =====
__global__ __launch_bounds__(256, 2) void pgemm_kernel(
    const ushort_t* __restrict__ Agh, const ushort_t* __restrict__ Agl,
    const ushort_t* __restrict__ Xh, const ushort_t* __restrict__ Xl,
    float* __restrict__ part) {
  __shared__ __align__(16) ushort_t sA[2][2][2][4][64][8];
  __shared__ __align__(16) ushort_t sB[2][2][2][4][64][8];
  const int t = threadIdx.x;
  const int l = t & 63;
  const int w = t >> 6;
  const int wm = w >> 1, wn = w & 1;
  const int m0 = blockIdx.y;
  const int n0 = blockIdx.x * 128;
  const int zk = blockIdx.z;
  const int kcb = zk * 162;

  int n = n0 + w * 32 + (l & 31);
  int b_ = n / 36;
  int pos = n - b_ * 36;
  int ph = pos / 6, pww = pos - ph * 6;
  size_t pbase = (((size_t)b_ * 20 + 2 * ph) * 20 + 2 * pww) * 256 + ((l >> 5) << 3);

  const int sw = w >> 1, klw = w & 1;
  const ushort_t* Asrc = sw ? Agl : Agh;
  const size_t aoff0 = (((size_t)(kcb + klw) * 8 + m0 * 4) * 64 + l) * 8;

  f32x16 acc[2][2];
#pragma unroll
  for (int j = 0; j < 2; ++j)
#pragma unroll
    for (int j2 = 0; j2 < 2; ++j2)
#pragma unroll
      for (int r = 0; r < 16; ++r) acc[j][j2][r] = 0.f;

  auto koff = [](int kc) {
    int kh = (unsigned)kc / 144u;
    int r = kc - kh * 144;
    return ((kh * 20 + (r >> 4)) << 8) + ((r & 15) << 4);
  };
  // exactly 8 vmem instructions per wave per stage call
  auto stage = [&](int buf, int step) {
    size_t ao = aoff0 + (size_t)step * 8192;
#pragma unroll
    for (int j = 0; j < 4; ++j)
      gl2lds16(Asrc + ao + j * 512, &sA[buf][sw][klw][j][0][0]);
    int kc0 = kcb + 2 * step;
    int o0 = koff(kc0), o1 = koff(kc0 + 1);
    gl2lds16(Xh + pbase + o0, &sB[buf][0][0][w][0][0]);
    gl2lds16(Xh + pbase + o1, &sB[buf][0][1][w][0][0]);
    gl2lds16(Xl + pbase + o0, &sB[buf][1][0][w][0][0]);
    gl2lds16(Xl + pbase + o1, &sB[buf][1][1][w][0][0]);
  };

  stage(0, 0);
  stage(1, 1);
  for (int step = 0; step < 81; ++step) {
    // wait only for THIS step's stage (leave next step's 8 loads in flight)
    if (step < 80)
      asm volatile("s_waitcnt vmcnt(8)" ::: "memory");
    else
      asm volatile("s_waitcnt vmcnt(0)" ::: "memory");
    __builtin_amdgcn_sched_barrier(0);
    __builtin_amdgcn_s_barrier();
    const int buf = step & 1;
    __builtin_amdgcn_s_setprio(1);
#pragma unroll
    for (int kl = 0; kl < 2; ++kl) {
      short8 a0h = *(const short8*)&sA[buf][0][kl][wm * 2 + 0][l][0];
      short8 a1h = *(const short8*)&sA[buf][0][kl][wm * 2 + 1][l][0];
      short8 a0l = *(const short8*)&sA[buf][1][kl][wm * 2 + 0][l][0];
      short8 a1l = *(const short8*)&sA[buf][1][kl][wm * 2 + 1][l][0];
      short8 b0h = *(const short8*)&sB[buf][0][kl][wn * 2 + 0][l][0];
      short8 b1h = *(const short8*)&sB[buf][0][kl][wn * 2 + 1][l][0];
      short8 b0l = *(const short8*)&sB[buf][1][kl][wn * 2 + 0][l][0];
      short8 b1l = *(const short8*)&sB[buf][1][kl][wn * 2 + 1][l][0];
      acc[0][0] = __builtin_amdgcn_mfma_f32_32x32x16_bf16(a0h, b0h, acc[0][0], 0, 0, 0);
      acc[0][0] = __builtin_amdgcn_mfma_f32_32x32x16_bf16(a0h, b0l, acc[0][0], 0, 0, 0);
      acc[0][0] = __builtin_amdgcn_mfma_f32_32x32x16_bf16(a0l, b0h, acc[0][0], 0, 0, 0);
      acc[0][1] = __builtin_amdgcn_mfma_f32_32x32x16_bf16(a0h, b1h, acc[0][1], 0, 0, 0);
      acc[0][1] = __builtin_amdgcn_mfma_f32_32x32x16_bf16(a0h, b1l, acc[0][1], 0, 0, 0);
      acc[0][1] = __builtin_amdgcn_mfma_f32_32x32x16_bf16(a0l, b1h, acc[0][1], 0, 0, 0);
      acc[1][0] = __builtin_amdgcn_mfma_f32_32x32x16_bf16(a1h, b0h, acc[1][0], 0, 0, 0);
      acc[1][0] = __builtin_amdgcn_mfma_f32_32x32x16_bf16(a1h, b0l, acc[1][0], 0, 0, 0);
      acc[1][0] = __builtin_amdgcn_mfma_f32_32x32x16_bf16(a1l, b0h, acc[1][0], 0, 0, 0);
      acc[1][1] = __builtin_amdgcn_mfma_f32_32x32x16_bf16(a1h, b1h, acc[1][1], 0, 0, 0);
      acc[1][1] = __builtin_amdgcn_mfma_f32_32x32x16_bf16(a1h, b1l, acc[1][1], 0, 0, 0);
      acc[1][1] = __builtin_amdgcn_mfma_f32_32x32x16_bf16(a1l, b1h, acc[1][1], 0, 0, 0);
    }
    __builtin_amdgcn_s_setprio(0);
    __builtin_amdgcn_s_barrier();
    __builtin_amdgcn_sched_barrier(0);
    if (step < 79) stage(buf, step + 2);
  }

#pragma unroll
  for (int j = 0; j < 2; ++j)
#pragma unroll
    for (int j2 = 0; j2 < 2; ++j2) {
      int ocb = m0 * 128 + wm * 64 + j * 32;
      int nb = n0 + wn * 64 + j2 * 32 + (l & 31);
#pragma unroll
      for (int r = 0; r < 16; ++r) {
        int row = (r & 3) + 8 * (r >> 2) + ((l >> 5) << 2);
        part[((size_t)(zk * 256 + ocb + row)) * 9216 + nb] = acc[j][j2][r];
      }
    }
}

// === u[b][oc*36+pos] = bias[oc] + sum_z part[z][oc][n], n = b*36+pos ========
__global__ __launch_bounds__(256) void ured_kernel(const float* __restrict__ part,
                                                   const float* __restrict__ pb,
                                                   float* __restrict__ u) {
  int tid = blockIdx.x * 256 + threadIdx.x;
  int oc = tid / 9216;
  int n = tid - oc * 9216;
  float s = pb[oc];
#pragma unroll
  for (int z = 0; z < 8; ++z) s += part[((size_t)z * 256 + oc) * 9216 + n];
  int b = n / 36;
  int pos = n - b * 36;
  u[(size_t)b * 9216 + oc * 36 + pos] = s;
}

// ======= squash + convert: u fp32 -> ub (b-major) & ut (k-major) hi/lo =====
__global__ __launch_bounds__(256) void sqcvt_kernel(const float* __restrict__ u,
                                                    ushort_t* __restrict__ ubh,
                                                    ushort_t* __restrict__ ubl,
                                                    ushort_t* __restrict__ uth,
                                                    ushort_t* __restrict__ utl) {
  int kt = blockIdx.x, bt = blockIdx.y;
  int k0 = kt * 64, b0 = bt * 64;
  __shared__ ushort_t lh[64][66], ll_[64][66];
  int t = threadIdx.x;
#pragma unroll
  for (int jj = 0; jj < 2; ++jj) {
    int item = t + 256 * jj;
    int g = item & 7, bl = item >> 3;
    int b = b0 + bl, kb = k0 + g * 8;
    const float4* p4 = reinterpret_cast<const float4*>(u + (size_t)b * 9216 + kb);
    float4 v0 = p4[0], v1 = p4[1];
    float va[8] = {v0.x, v0.y, v0.z, v0.w, v1.x, v1.y, v1.z, v1.w};
    float sn = 0.f;
#pragma unroll
    for (int e = 0; e < 8; ++e) sn += va[e] * va[e];
    float f = sn / ((1.f + sn) * sqrtf(sn));
    short8 sh, sl;
#pragma unroll
    for (int e = 0; e < 8; ++e) {
      float vv = va[e] * f;
      unsigned short h = f2bf(vv);
      unsigned short lo = f2bf(vv - bf2f(h));
      sh[e] = (short)h;
      sl[e] = (short)lo;
      lh[g * 8 + e][bl] = h;
      ll_[g * 8 + e][bl] = lo;
    }
    *(short8*)&ubh[(size_t)b * 9216 + kb] = sh;
    *(short8*)&ubl[(size_t)b * 9216 + kb] = sl;
  }
  __syncthreads();
  int kl = t >> 2, br = (t & 3) * 16;
#pragma unroll
  for (int q = 0; q < 2; ++q) {
    short8 sh, sl;
#pragma unroll
    for (int e = 0; e < 8; ++e) {
      sh[e] = (short)lh[kl][br + q * 8 + e];
      sl[e] = (short)ll_[kl][br + q * 8 + e];
    }
    *(short8*)&uth[(size_t)(k0 + kl) * 256 + b0 + br + q * 8] = sh;
    *(short8*)&utl[(size_t)(k0 + kl) * 256 + b0 + br + q * 8] = sl;
  }
}

// ================================ helpers ==================================
__global__ void zero_kernel(float* __restrict__ p, int n) {
  int i = blockIdx.x * 256 + threadIdx.x;
  if (i < n) p[i] = 0.f;
}

__global__ __launch_bounds__(256) void softmax_c_kernel(const float* __restrict__ bp,
                                                        float* __restrict__ c) {
  int cls = blockIdx.x;
  int t = threadIdx.x;
  __shared__ float red[256];
  float m = -1e30f;
  for (int r = t; r < 1152; r += 256) m = fmaxf(m, bp[r * 10 + cls]);
  red[t] = m;
  __syncthreads();
  for (int s = 128; s > 0; s >>= 1) {
    if (t < s) red[t] = fmaxf(red[t], red[t + s]);
    __syncthreads();
  }
  m = red[0];
  __syncthreads();
  float sum = 0.f;
  for (int r = t; r < 1152; r += 256) sum += expf(bp[r * 10 + cls] - m);
  red[t] = sum;
  __syncthreads();
  for (int s = 128; s > 0; s >>= 1) {
    if (t < s) red[t] += red[t + s];
    __syncthreads();
  }
  float den = red[0];
  for (int r = t; r < 1152; r += 256) c[r * 10 + cls] = expf(bp[r * 10 + cls] - m) / den;
}

// WCb[col 160][k 9216] bf16 hi/lo, col=cls*16+o, k=r*8+i; val = W*c
__global__ __launch_bounds__(256) void wcb_kernel(const float* __restrict__ W,
                                                  const float* __restrict__ c,
                                                  ushort_t* __restrict__ wh,
                                                  ushort_t* __restrict__ wl) {
  int tid = blockIdx.x * 256 + threadIdx.x;  // 184320 = 160*1152
  int col = tid / 1152;
  int kg = tid - col * 1152;  // = r
  int cls = col >> 4, o = col & 15;
  float cc = c[kg * 10 + cls];
  const float4* wp = reinterpret_cast<const float4*>(W + (((size_t)kg * 10 + cls) * 16 + o) * 8);
  float4 w0 = wp[0], w1 = wp[1];
  float wa[8] = {w0.x, w0.y, w0.z, w0.w, w1.x, w1.y, w1.z, w1.w};
  short8 sh, sl;
#pragma unroll
  for (int e = 0; e < 8; ++e) {
    float vv = wa[e] * cc;
    unsigned short h = f2bf(vv);
    sh[e] = (short)h;
    sl[e] = (short)f2bf(vv - bf2f(h));
  }
  *(short8*)&wh[(size_t)col * 9216 + kg * 8] = sh;
  *(short8*)&wl[(size_t)col * 9216 + kg * 8] = sl;
}

// ====== s-GEMM via MFMA, per-lane register fragments, no LDS ===============
// grid (144 ks, 4 bt, 5 cf), 64 thr; s_part[ks][b 256][col 160]
__global__ __launch_bounds__(64) void smfma_kernel(
    const ushort_t* __restrict__ ubh, const ushort_t* __restrict__ ubl,
    const ushort_t* __restrict__ wh, const ushort_t* __restrict__ wl,
    float* __restrict__ s_part) {
  int ks = blockIdx.x, bt = blockIdx.y, cf = blockIdx.z;
  int l = threadIdx.x;
  int k0 = ks * 64;
  int kf = ((l >> 5) << 3);
  f32x16 acc[2];
#pragma unroll
  for (int m = 0; m < 2; ++m)
#pragma unroll
    for (int r = 0; r < 16; ++r) acc[m][r] = 0.f;
#pragma unroll
  for (int kc = 0; kc < 4; ++kc) {
    size_t bo = (size_t)(cf * 32 + (l & 31)) * 9216 + k0 + kc * 16 + kf;
    short8 bh = *(const short8*)&wh[bo];
    short8 bl = *(const short8*)&wl[bo];
#pragma unroll
    for (int mh = 0; mh < 2; ++mh) {
      size_t ao = (size_t)(bt * 64 + mh * 32 + (l & 31)) * 9216 + k0 + kc * 16 + kf;
      short8 ah = *(const short8*)&ubh[ao];
      short8 al = *(const short8*)&ubl[ao];
      acc[mh] = __builtin_amdgcn_mfma_f32_32x32x16_bf16(ah, bh, acc[mh], 0, 0, 0);
      acc[mh] = __builtin_amdgcn_mfma_f32_32x32x16_bf16(ah, bl, acc[mh], 0, 0, 0);
      acc[mh] = __builtin_amdgcn_mfma_f32_32x32x16_bf16(al, bh, acc[mh], 0, 0, 0);
    }
  }
#pragma unroll
  for (int mh = 0; mh < 2; ++mh)
#pragma unroll
    for (int r = 0; r < 16; ++r) {
      int row = bt * 64 + mh * 32 + (r & 3) + 8 * (r >> 2) + ((l >> 5) << 2);
      s_part[((size_t)ks * 256 + row) * 160 + cf * 32 + (l & 31)] = acc[mh][r];
    }
}

// v = f(sum of 144 partials); also vT bf16 hi/lo; optional out
__global__ __launch_bounds__(256) void reduce_v_kernel(
    const float* __restrict__ s_part, float* __restrict__ v,
    ushort_t* __restrict__ vth, ushort_t* __restrict__ vtl,
    float* __restrict__ out, int write_out) {
  int i = blockIdx.x * 256 + threadIdx.x;  // 40960
  float s0 = 0.f, s1 = 0.f, s2 = 0.f, s3 = 0.f;
#pragma unroll 4
  for (int ks = 0; ks < 144; ks += 4) {
    s0 += s_part[(size_t)ks * 40960 + i];
    s1 += s_part[(size_t)(ks + 1) * 40960 + i];
    s2 += s_part[(size_t)(ks + 2) * 40960 + i];
    s3 += s_part[(size_t)(ks + 3) * 40960 + i];
  }
  float s = (s0 + s1) + (s2 + s3);
  float val = s * fabsf(s) / (1.f + s * s);
  v[i] = val;
  int b = i / 160, col = i - b * 160;
  unsigned short h = f2bf(val);
  vth[col * 256 + b] = h;
  vtl[col * 256 + b] = f2bf(val - bf2f(h));
  if (write_out) out[i] = val;
}

// ====== T-GEMM via MFMA, per-lane register fragments, no LDS ===============
// grid (288 mt of 32 k-rows, 5 cf), 64 thr; T[k 9216][col 160]
__global__ __launch_bounds__(64) void tmfma_kernel(
    const ushort_t* __restrict__ uth, const ushort_t* __restrict__ utl,
    const ushort_t* __restrict__ vth, const ushort_t* __restrict__ vtl,
    float* __restrict__ T) {
  int mt = blockIdx.x, cf = blockIdx.y;
  int l = threadIdx.x;
  int m0 = mt * 32;
  int bf = ((l >> 5) << 3);
  f32x16 acc;
#pragma unroll
  for (int r = 0; r < 16; ++r) acc[r] = 0.f;
  for (int step = 0; step < 16; ++step) {
    size_t ao = (size_t)(m0 + (l & 31)) * 256 + step * 16 + bf;
    size_t bo = (size_t)(cf * 32 + (l & 31)) * 256 + step * 16 + bf;
    short8 ah = *(const short8*)&uth[ao];
    short8 al = *(const short8*)&utl[ao];
    short8 bh = *(const short8*)&vth[bo];
    short8 bl = *(const short8*)&vtl[bo];
    acc = __builtin_amdgcn_mfma_f32_32x32x16_bf16(ah, bh, acc, 0, 0, 0);
    acc = __builtin_amdgcn_mfma_f32_32x32x16_bf16(ah, bl, acc, 0, 0, 0);
    acc = __builtin_amdgcn_mfma_f32_32x32x16_bf16(al, bh, acc, 0, 0, 0);
  }
  const float scl = 1.f / 256.f;
#pragma unroll
  for (int r = 0; r < 16; ++r) {
    int row = (r & 3) + 8 * (r >> 2) + ((l >> 5) << 2);
    T[(size_t)(m0 + row) * 160 + cf * 32 + (l & 31)] = acc[r] * scl;
  }
}

// bp[r,cls] += sum_{o,i} W[r,cls,o,i] * T[(r,i),(cls,o)]
__global__ __launch_bounds__(256) void bp_update_kernel(const float* __restrict__ W,
                                                        const float* __restrict__ T,
                                                        float* __restrict__ bp) {
  int idx = blockIdx.x * 256 + threadIdx.x;
  if (idx >= 11520) return;
  int r = idx / 10, cls = idx % 10;
  const float* wp = W + (size_t)idx * 128;
  float s = 0.f;
#pragma unroll
  for (int o = 0; o < 16; ++o)
#pragma unroll
    for (int i = 0; i < 8; ++i)
      s = fmaf(wp[o * 8 + i], T[(size_t)(r * 8 + i) * 160 + cls * 16 + o], s);
  bp[idx] += s;
}

// class norms -> softmax over batch -> argmax -> masked + (bi, tsel)
__global__ __launch_bounds__(256) void mask_kernel(const float* __restrict__ v,
                                                   float* __restrict__ masked,
                                                   int* __restrict__ bi_out,
                                                   float* __restrict__ tsel) {
  __shared__ float cls_s[256][10];
  __shared__ float colmax[10], colden[10];
  int t = threadIdx.x;
  float cl[10];
  for (int c = 0; c < 10; ++c) {
    float sum = 0.f;
    for (int o = 0; o < 16; ++o) {
      float q = v[t * 160 + c * 16 + o];
      sum += q * q;
    }
    cl[c] = sqrtf(sum);
    cls_s[t][c] = cl[c];
  }
  __syncthreads();
  if (t < 10) {
    float m = -1e30f;
    for (int b = 0; b < 256; ++b) m = fmaxf(m, cls_s[b][t]);
    float d = 0.f;
    for (int b = 0; b < 256; ++b) d += expf(cls_s[b][t] - m);
    colmax[t] = m;
    colden[t] = d;
  }
  __syncthreads();
  float best = -1e30f;
  int bi = 0;
  for (int c = 0; c < 10; ++c) {
    float p = expf(cl[c] - colmax[c]) / colden[c];
    if (p > best) { best = p; bi = c; }
  }
  for (int c = 0; c < 10; ++c) masked[t * 10 + c] = (c == bi) ? 1.f : 0.f;
  bi_out[t] = bi;
  for (int o = 0; o < 16; ++o) tsel[t * 16 + o] = v[t * 160 + bi * 16 + o];
}

// fc1 exploiting mask sparsity: K=16
__global__ __launch_bounds__(256) void fc1s_kernel(const float* __restrict__ tsel,
                                                   const int* __restrict__ bi,
                                                   const float* __restrict__ w1,
                                                   const float* __restrict__ b1,
                                                   float* __restrict__ h1) {
  int b = blockIdx.x;
  int t = threadIdx.x;
  __shared__ float ts[16];
  __shared__ int sbi;
  if (t < 16) ts[t] = tsel[b * 16 + t];
  if (t == 0) sbi = bi[b];
  __syncthreads();
  for (int j = t; j < 512; j += 256) {
    const float* wp = w1 + (size_t)j * 160 + sbi * 16;
    float a = b1[j];
#pragma unroll
    for (int o = 0; o < 16; ++o) a = fmaf(ts[o], wp[o], a);
    h1[(size_t)b * 512 + j] = fmaxf(a, 0.f);
  }
}

template <int ACT>
__global__ __launch_bounds__(256) void fc_kernel(const float* __restrict__ in,
                                                 const float* __restrict__ w,
                                                 const float* __restrict__ bias,
                                                 float* __restrict__ out, int K, int N) {
  int jt = blockIdx.x, bt = blockIdx.y;
  __shared__ float in_s[16][33];
  __shared__ float w_s[64][33];
  int t = threadIdx.x;
  int jl = t & 63, bq = t >> 6;
  float acc[4] = {0, 0, 0, 0};
  for (int k0 = 0; k0 < K; k0 += 32) {
    __syncthreads();
    for (int q = t; q < 512; q += 256) {
      int bb = q >> 5, kk = q & 31;
      in_s[bb][kk] = in[(size_t)(bt * 16 + bb) * K + k0 + kk];
    }
    for (int q = t; q < 2048; q += 256) {
      int jj = q >> 5, kk = q & 31;
      int jg = jt * 64 + jj;
      w_s[jj][kk] = (jg < N) ? w[(size_t)jg * K + k0 + kk] : 0.f;
    }
    __syncthreads();
#pragma unroll
    for (int kk = 0; kk < 32; ++kk) {
      float wv = w_s[jl][kk];
#pragma unroll
      for (int m = 0; m < 4; ++m) acc[m] = fmaf(in_s[bq * 4 + m][kk], wv, acc[m]);
    }
  }
  int jg = jt * 64 + jl;
  if (jg < N) {
    float bv = bias[jg];
    for (int m = 0; m < 4; ++m) {
      float r = acc[m] + bv;
      if (ACT == 0)
        r = fmaxf(r, 0.f);
      else
        r = 1.f / (1.f + expf(-r));
      out[(size_t)(bt * 16 + bq * 4 + m) * N + jg] = r;
    }
  }
}

// ===========================================================================
extern "C" void kernel_launch(void* const* d_in, const int* in_sizes, int n_in,
                              void* d_out, int out_size, void* d_ws, size_t ws_size,
                              hipStream_t stream) {
  const float* data  = (const float*)d_in[0];
  const float* convw = (const float*)d_in[1];
  const float* convb = (const float*)d_in[2];
  const float* pcw   = (const float*)d_in[3];
  const float* pcb   = (const float*)d_in[4];
  const float* W     = (const float*)d_in[5];
  const float* w1    = (const float*)d_in[6];
  const float* b1    = (const float*)d_in[7];
  const float* w2    = (const float*)d_in[8];
  const float* b2    = (const float*)d_in[9];
  const float* w3    = (const float*)d_in[10];
  const float* b3    = (const float*)d_in[11];
  float* out = (float*)d_out;

  char* wsb = (char*)d_ws;
  size_t off = 0;
  auto allocb = [&](size_t bytes) {
    void* p = wsb + off;
    off += (bytes + 255) & ~(size_t)255;
    return p;
  };
  // region 0: pgemm partials (phase A) -> ub/ut bf16 (phase B)
  float* part = (float*)allocb(75497472);  // 8*256*9216*4
  ushort_t* ubh = (ushort_t*)part;
  ushort_t* ubl = ubh + 2359296;
  ushort_t* uth = ubl + 2359296;
  ushort_t* utl = uth + 2359296;
  float* u    = (float*)allocb(9437184);   // (256,9216) fp32
  float* v    = (float*)allocb(163840);
  float* bp   = (float*)allocb(46080);
  float* c    = (float*)allocb(46080);
  ushort_t* WCbh = (ushort_t*)allocb(2949120);
  ushort_t* WCbl = (ushort_t*)allocb(2949120);
  ushort_t* vth  = (ushort_t*)allocb(81920);
  ushort_t* vtl  = (ushort_t*)allocb(81920);
  int*   bi   = (int*)allocb(1024);
  float* tsel = (float*)allocb(16384);
  // s_part (during smfma/reduce) / T (after reduce) / h1,h2 (tail)
  float* s_part = (float*)allocb(23592960);  // 144*256*160*4
  float* T  = s_part;                        // 9216*160*4 = 5.9MB
  float* h1 = s_part;                        // 256*512*4
  float* h2 = s_part + 131072;               // 256*1024*4
  ushort_t* Agh = (ushort_t*)allocb(10616832);
  ushort_t* Agl = (ushort_t*)allocb(10616832);
  ushort_t* Afch = (ushort_t*)allocb(147456);
  ushort_t* Afcl = (ushort_t*)allocb(147456);
  ushort_t* xTh = (ushort_t*)allocb(52428800);  // [n=102400][256] bf16 hi
  ushort_t* xTl = (ushort_t*)allocb(52428800);
  if (ws_size < off) return;

  acvt_kernel<<<18, 256, 0, stream>>>(convw, Afch, Afcl);
  cgemm_kernel<<<1600, 256, 0, stream>>>(Afch, Afcl, data, convb, xTh, xTl);
  wcvt_kernel<<<2592, 256, 0, stream>>>(pcw, Agh, Agl);
  pgemm_kernel<<<dim3(72, 2, 8), 256, 0, stream>>>(Agh, Agl, xTh, xTl, part);
  ured_kernel<<<9216, 256, 0, stream>>>(part, pcb, u);
  sqcvt_kernel<<<dim3(144, 4), 256, 0, stream>>>(u, ubh, ubl, uth, utl);
  zero_kernel<<<45, 256, 0, stream>>>(bp, 11520);

  for (int it = 0; it < 3; ++it) {
    softmax_c_kernel<<<10, 256, 0, stream>>>(bp, c);
    wcb_kernel<<<720, 256, 0, stream>>>(W, c, WCbh, WCbl);
    smfma_kernel<<<dim3(144, 4, 5), 64, 0, stream>>>(ubh, ubl, WCbh, WCbl, s_part);
    reduce_v_kernel<<<160, 256, 0, stream>>>(s_part, v, vth, vtl, out, it == 2 ? 1 : 0);
    if (it < 2) {
      tmfma_kernel<<<dim3(288, 5), 64, 0, stream>>>(uth, utl, vth, vtl, T);
      bp_update_kernel<<<45, 256, 0, stream>>>(W, T, bp);
    }
  }

  mask_kernel<<<1, 256, 0, stream>>>(v, out + 241664, bi, tsel);
  fc1s_kernel<<<256, 256, 0, stream>>>(tsel, bi, w1, b1, h1);
  fc_kernel<0><<<dim3(16, 16), 256, 0, stream>>>(h1, w2, b2, h2, 512, 1024);
  fc_kernel<1><<<dim3(13, 16), 256, 0, stream>>>(h2, w3, b3, out + 40960, 1024, 784);
}